// Round 4
// baseline (1447.545 us; speedup 1.0000x reference)
//
#include <hip/hip_runtime.h>
#include <hip/hip_bf16.h>
#include <cstdint>
#include <cstddef>

#define DEV __device__ __forceinline__

constexpr int Bb = 2, Ls = 4096, Dd = 2048, Hh = 32, HD = 64, MBK = 16, NMBc = 256;
constexpr int MTOK = Bb * Ls; // 8192 tokens

typedef __bf16 bf16x8 __attribute__((ext_vector_type(8)));
typedef float  f32x4  __attribute__((ext_vector_type(4)));

// hardware RNE f32->bf16
DEV unsigned short f2bf(float f) {
    union { __bf16 h; unsigned short u; } x;
    x.h = (__bf16)f;
    return x.u;
}
DEV float b2f(unsigned short u) {
    union { unsigned int i; float f; } x; x.i = ((unsigned int)u) << 16;
    return x.f;
}

// 64-lane sum via DPP; lane 63 holds total, readlane broadcasts (uniform use).
DEV float wsum64(float v) {
    int t;
    t = __builtin_amdgcn_update_dpp(0, __float_as_int(v), 0x111, 0xf, 0xf, true); v += __int_as_float(t);
    t = __builtin_amdgcn_update_dpp(0, __float_as_int(v), 0x112, 0xf, 0xf, true); v += __int_as_float(t);
    t = __builtin_amdgcn_update_dpp(0, __float_as_int(v), 0x114, 0xf, 0xf, true); v += __int_as_float(t);
    t = __builtin_amdgcn_update_dpp(0, __float_as_int(v), 0x118, 0xf, 0xf, true); v += __int_as_float(t);
    t = __builtin_amdgcn_update_dpp(0, __float_as_int(v), 0x142, 0xa, 0xf, true); v += __int_as_float(t);
    t = __builtin_amdgcn_update_dpp(0, __float_as_int(v), 0x143, 0xc, 0xf, true); v += __int_as_float(t);
    return __int_as_float(__builtin_amdgcn_readlane(__float_as_int(v), 63));
}

// 16-lane (DPP row) rotate-reduce sum: every lane of each row-of-16 gets the row total.
DEV float rsum16(float v) {
    int t;
    t = __builtin_amdgcn_update_dpp(0, __float_as_int(v), 0x121, 0xf, 0xf, true); v += __int_as_float(t); // ror1
    t = __builtin_amdgcn_update_dpp(0, __float_as_int(v), 0x122, 0xf, 0xf, true); v += __int_as_float(t); // ror2
    t = __builtin_amdgcn_update_dpp(0, __float_as_int(v), 0x124, 0xf, 0xf, true); v += __int_as_float(t); // ror4
    t = __builtin_amdgcn_update_dpp(0, __float_as_int(v), 0x128, 0xf, 0xf, true); v += __int_as_float(t); // ror8
    return v;
}

// 4-lane quad sum via quad_perm DPP: every lane of each group-of-4 gets the total.
DEV float qsum4(float v) {
    int t;
    t = __builtin_amdgcn_update_dpp(0, __float_as_int(v), 0xB1, 0xf, 0xf, true); v += __int_as_float(t); // [1,0,3,2]
    t = __builtin_amdgcn_update_dpp(0, __float_as_int(v), 0x4E, 0xf, 0xf, true); v += __int_as_float(t); // [2,3,0,1]
    return v;
}

// runtime-n select from 4 scalars (no dynamic indexing -> no scratch)
DEV float sel4(int n, float a, float b, float c, float d) {
    float v = (n == 1) ? b : a;
    v = (n == 2) ? c : v;
    v = (n == 3) ? d : v;
    return v;
}

DEV void g2l16(const void* g, void* l) {
    __builtin_amdgcn_global_load_lds(
        (__attribute__((address_space(1))) void*)(g),
        (__attribute__((address_space(3))) void*)(l), 16, 0, 0);
}

// ---------------- cast hidden_states fp32 -> bf16 ----------------
__global__ __launch_bounds__(256) void cast_hs_kernel(const float* __restrict__ src,
                                                      unsigned short* __restrict__ dst) {
    int i = (blockIdx.x * 256 + threadIdx.x) * 4;
    float4 v = *(const float4*)(src + i);
    ushort4 o; o.x = f2bf(v.x); o.y = f2bf(v.y); o.z = f2bf(v.z); o.w = f2bf(v.w);
    *(ushort4*)(dst + i) = o;
}

// ---------------- transpose + cast weight: W[k][n] fp32 -> Wt[n][k] bf16 ----------------
__global__ __launch_bounds__(256) void transpose_cast_kernel(const float* __restrict__ W,
                                                             unsigned short* __restrict__ Wt) {
    __shared__ float tile[64][65];
    int bx = blockIdx.x & 31;   // k-tile
    int by = blockIdx.x >> 5;   // n-tile
    int t = threadIdx.x;
    int r = t >> 4, c4 = (t & 15) * 4;
    #pragma unroll
    for (int i = 0; i < 4; ++i) {
        int row = r + i * 16;
        float4 v = *(const float4*)(W + (size_t)(bx * 64 + row) * Dd + by * 64 + c4);
        tile[row][c4 + 0] = v.x; tile[row][c4 + 1] = v.y;
        tile[row][c4 + 2] = v.z; tile[row][c4 + 3] = v.w;
    }
    __syncthreads();
    #pragma unroll
    for (int i = 0; i < 4; ++i) {
        int row = r + i * 16; // n index
        ushort4 o;
        o.x = f2bf(tile[c4 + 0][row]); o.y = f2bf(tile[c4 + 1][row]);
        o.z = f2bf(tile[c4 + 2][row]); o.w = f2bf(tile[c4 + 3][row]);
        *(ushort4*)(Wt + (size_t)(by * 64 + row) * Dd + bx * 64 + c4) = o;
    }
}

// ---------------- bf16 MFMA GEMM:  C[M,N] = A[M,K] @ Bt[N,K]^T + bias ----------------
__global__ __launch_bounds__(256) void gemm_bt_kernel(const unsigned short* __restrict__ A,
                                                      const unsigned short* __restrict__ Bt,
                                                      const float* __restrict__ bias,
                                                      float* __restrict__ C,
                                                      int M, int N, int Kd) {
    __shared__ unsigned short sA[128 * 64];
    __shared__ unsigned short sB[128 * 64];
    int t = threadIdx.x;
    int lane = t & 63;
    int wid = t >> 6, wm = wid >> 1, wn = wid & 1;
    int quad = lane >> 4, c = lane & 15;
    int bm = blockIdx.x, bn = blockIdx.y;

    const unsigned short* pa[4]; const unsigned short* pb[4];
    unsigned short* la[4]; unsigned short* lb[4];
    #pragma unroll
    for (int i = 0; i < 4; ++i) {
        int lin = i * 256 + t;
        int row = lin >> 3, blk = lin & 7;
        int oct = blk ^ (row & 7);
        pa[i] = A  + (size_t)(bm * 128 + row) * Kd + oct * 8;
        pb[i] = Bt + (size_t)(bn * 128 + row) * Kd + oct * 8;
        la[i] = sA + lin * 8;
        lb[i] = sB + lin * 8;
    }

    f32x4 acc[4][4];
    #pragma unroll
    for (int i = 0; i < 4; ++i)
        #pragma unroll
        for (int j = 0; j < 4; ++j)
            #pragma unroll
            for (int r = 0; r < 4; ++r) acc[i][j][r] = 0.f;

    const char* sAc = (const char*)sA;
    const char* sBc = (const char*)sB;
    int rowA0 = wm * 64 + c, rowB0 = wn * 64 + c;
    int sw = (c & 7);

    int nkt = Kd >> 6;
    for (int kt = 0; kt < nkt; ++kt) {
        #pragma unroll
        for (int i = 0; i < 4; ++i) {
            g2l16(pa[i], la[i]);
            g2l16(pb[i], lb[i]);
            pa[i] += 64; pb[i] += 64;
        }
        __syncthreads();
        #pragma unroll
        for (int s = 0; s < 2; ++s) {
            bf16x8 af[4], bfv[4];
            int so = (s << 2) | quad;
            #pragma unroll
            for (int mt = 0; mt < 4; ++mt)
                af[mt] = *(const bf16x8*)(sAc + (rowA0 + mt * 16) * 128 + ((so ^ sw) * 16));
            #pragma unroll
            for (int nt = 0; nt < 4; ++nt)
                bfv[nt] = *(const bf16x8*)(sBc + (rowB0 + nt * 16) * 128 + ((so ^ sw) * 16));
            #pragma unroll
            for (int mt = 0; mt < 4; ++mt)
                #pragma unroll
                for (int nt = 0; nt < 4; ++nt)
                    acc[mt][nt] = __builtin_amdgcn_mfma_f32_16x16x32_bf16(af[mt], bfv[nt], acc[mt][nt], 0, 0, 0);
        }
        __syncthreads();
    }

    float bv[4];
    #pragma unroll
    for (int nt = 0; nt < 4; ++nt) bv[nt] = bias[bn * 128 + wn * 64 + nt * 16 + c];
    #pragma unroll
    for (int mt = 0; mt < 4; ++mt)
        #pragma unroll
        for (int r = 0; r < 4; ++r) {
            int row = bm * 128 + wm * 64 + mt * 16 + quad * 4 + r;
            float* cp = C + (size_t)row * N + bn * 128 + wn * 64 + c;
            #pragma unroll
            for (int nt = 0; nt < 4; ++nt) cp[nt * 16] = acc[mt][nt][r] + bv[nt];
        }
}

// ---------------- lr: s[b,h,l] = sigmoid(hs[b,l,:]·lr_w[h,:] + lr_b[h]) / (HD*K) ----------------
__global__ __launch_bounds__(256) void lr_kernel(const float* __restrict__ hs,
                                                 const float* __restrict__ lrw,
                                                 const float* __restrict__ lrb,
                                                 float* __restrict__ lr_out) {
    int tok = blockIdx.x; // b*L + l
    int t = threadIdx.x;
    int h = t >> 3, j0 = t & 7;
    const float* row = hs + (size_t)tok * Dd;
    const float* wr = lrw + (size_t)h * Dd;
    float p = 0.f;
    for (int j = j0 * 4; j < Dd; j += 32) {
        float4 a = *(const float4*)(row + j);
        float4 w = *(const float4*)(wr + j);
        p += a.x * w.x + a.y * w.y + a.z * w.z + a.w * w.w;
    }
    __shared__ float red[32][8];
    red[h][j0] = p;
    __syncthreads();
    if (t < 32) {
        float s = 0.f;
        #pragma unroll
        for (int i = 0; i < 8; ++i) s += red[t][i];
        s += lrb[t];
        s = 1.f / (1.f + expf(-s));
        s *= 1.0f / (HD * MBK);
        int b = tok >> 12, l = tok & (Ls - 1);
        lr_out[(size_t)(b * Hh + t) * Ls + l] = s;
    }
}

// ---------------- attn precompute: attG[bh][nmb][i][j] = masked -sv_j*(qn_i·kn_j + 1) bf16 ----------------
// One wave per 16x16 tile; 4 tiles per block. Massively parallel (all CUs), removes
// the wave-0-only attn work from the serial scan.
__global__ __launch_bounds__(256) void attn_kernel(const float* __restrict__ XQ,
                                                   const float* __restrict__ XK,
                                                   const float* __restrict__ lrbuf,
                                                   unsigned short* __restrict__ attG) {
    __shared__ unsigned short qb[4][16 * 72];
    __shared__ unsigned short kb[4][16 * 72];
    int t = threadIdx.x, w = t >> 6, lane = t & 63;
    int gid = blockIdx.x * 4 + w;       // tile id
    int bh = gid >> 8, nmb = gid & 255; // 256 tiles per chain
    int b = bh >> 5, h = bh & 31;
    int l0 = nmb * 16;
    int tok = lane >> 2, fq = lane & 3; // lane covers feats fq*16..fq*16+15 of token tok
    size_t base = ((size_t)(b * Ls) + l0 + tok) * Dd + h * 64 + fq * 16;
    float4 qv[4], kv[4];
    #pragma unroll
    for (int i = 0; i < 4; ++i) {
        qv[i] = *(const float4*)(XQ + base + 4 * i);
        kv[i] = *(const float4*)(XK + base + 4 * i);
    }
    float sq = 0.f, sk = 0.f;
    #pragma unroll
    for (int i = 0; i < 4; ++i) {
        sq += qv[i].x * qv[i].x + qv[i].y * qv[i].y + qv[i].z * qv[i].z + qv[i].w * qv[i].w;
        sk += kv[i].x * kv[i].x + kv[i].y * kv[i].y + kv[i].z * kv[i].z + kv[i].w * kv[i].w;
    }
    float rq = 1.f / fmaxf(sqrtf(qsum4(sq)), 1e-12f);
    float rk = 1.f / fmaxf(sqrtf(qsum4(sk)), 1e-12f);
    #pragma unroll
    for (int i = 0; i < 4; ++i) {
        ushort4 oq, ok;
        oq.x = f2bf(qv[i].x * rq); oq.y = f2bf(qv[i].y * rq);
        oq.z = f2bf(qv[i].z * rq); oq.w = f2bf(qv[i].w * rq);
        ok.x = f2bf(kv[i].x * rk); ok.y = f2bf(kv[i].y * rk);
        ok.z = f2bf(kv[i].z * rk); ok.w = f2bf(kv[i].w * rk);
        *(ushort4*)&qb[w][tok * 72 + fq * 16 + 4 * i] = oq;
        *(ushort4*)&kb[w][tok * 72 + fq * 16 + 4 * i] = ok;
    }
    __syncthreads();
    int q2 = lane >> 4, n = lane & 15;
    bf16x8 qf0 = *(const bf16x8*)&qb[w][n * 72 + 8 * q2];
    bf16x8 qf1 = *(const bf16x8*)&qb[w][n * 72 + 32 + 8 * q2];
    bf16x8 kf0 = *(const bf16x8*)&kb[w][n * 72 + 8 * q2];
    bf16x8 kf1 = *(const bf16x8*)&kb[w][n * 72 + 32 + 8 * q2];
    const f32x4 zero4 = {0.f, 0.f, 0.f, 0.f};
    f32x4 a = __builtin_amdgcn_mfma_f32_16x16x32_bf16(qf1, kf1, zero4, 0, 0, 0);
    a = __builtin_amdgcn_mfma_f32_16x16x32_bf16(qf0, kf0, a, 0, 0, 0);
    float svn = lrbuf[(size_t)bh * Ls + l0 + n];
    unsigned short* op = attG + ((size_t)bh * NMBc + nmb) * 256;
    #pragma unroll
    for (int r = 0; r < 4; ++r) {
        int i = 4 * q2 + r;
        float v = (i >= n) ? (-svn * (a[r] + 1.f)) : 0.f;
        op[i * 16 + n] = f2bf(v);
    }
}

// staging-time fixup: L2-normalize q,k; v <- ln(v-k)+k. Row = 16 lanes x float4.
DEV void stage_qkv(float4 q, float4 k, float4 v,
                   float* tq, float* tk, float* tv,
                   unsigned short* bq, unsigned short* bk,
                   int rowp, int c4p, float4 lnw4, float4 lnb4) {
    float rq = 1.f / fmaxf(sqrtf(rsum16(q.x*q.x + q.y*q.y + q.z*q.z + q.w*q.w)), 1e-12f);
    q.x *= rq; q.y *= rq; q.z *= rq; q.w *= rq;
    float rk = 1.f / fmaxf(sqrtf(rsum16(k.x*k.x + k.y*k.y + k.z*k.z + k.w*k.w)), 1e-12f);
    k.x *= rk; k.y *= rk; k.z *= rk; k.w *= rk;
    float4 df; df.x = v.x - k.x; df.y = v.y - k.y; df.z = v.z - k.z; df.w = v.w - k.w;
    float mu = rsum16(df.x + df.y + df.z + df.w) * (1.f / 64.f);
    float4 cc; cc.x = df.x - mu; cc.y = df.y - mu; cc.z = df.z - mu; cc.w = df.w - mu;
    float var = rsum16(cc.x*cc.x + cc.y*cc.y + cc.z*cc.z + cc.w*cc.w) * (1.f / 63.f); // ddof=1
    float rs = 1.f / (sqrtf(var) + 1e-8f);
    float4 vn;
    vn.x = lnw4.x * cc.x * rs + lnb4.x + k.x;
    vn.y = lnw4.y * cc.y * rs + lnb4.y + k.y;
    vn.z = lnw4.z * cc.z * rs + lnb4.z + k.z;
    vn.w = lnw4.w * cc.w * rs + lnb4.w + k.w;
    *(float4*)&tq[rowp * 68 + c4p] = q;
    *(float4*)&tk[rowp * 68 + c4p] = k;
    *(float4*)&tv[rowp * 68 + c4p] = vn;
    ushort4 qb, kb;
    qb.x = f2bf(q.x); qb.y = f2bf(q.y); qb.z = f2bf(q.z); qb.w = f2bf(q.w);
    kb.x = f2bf(k.x); kb.y = f2bf(k.y); kb.z = f2bf(k.z); kb.w = f2bf(k.w);
    *(ushort4*)&bq[rowp * 72 + c4p] = qb;
    *(ushort4*)&bk[rowp * 72 + c4p] = kb;
}

// ---------------- MFMA TTT scan: 4 waves per (b,h) chain ----------------
// Wave w owns output-column slab S_w = [16w, 16w+16).
// Phase A: frags + z1/zb MFMAs + zTr row-major bounce + C-layout s1/s2 partials (rsum16).
// Phase B: grad LN using precombined s1/s2 (only sg/sxg wsum64 remain) -> gbufT/sxkT/pb.
// Phase C: zb finish + zbar (C-layout) + LN partials + W1 update + xq C-layout reg carry.
// Phase D: combine partials, LN, store Y from C-layout (no zbT bounce).
// attn precomputed (attG); attb staged per step via prefetch regs. 3 barriers/step.
__global__ __launch_bounds__(256, 1) void scan_kernel(const float* __restrict__ XQ,
                                                      const float* __restrict__ XK,
                                                      const float* __restrict__ XV,
                                                      const float* __restrict__ lrbuf,
                                                      const unsigned short* __restrict__ attG,
                                                      const float* __restrict__ W1in,
                                                      const float* __restrict__ b1in,
                                                      const float* __restrict__ lnw_g,
                                                      const float* __restrict__ lnb_g,
                                                      float* __restrict__ Y) {
    int bh = blockIdx.x;          // b*H + h
    int b = bh >> 5, h = bh & 31;
    int t = threadIdx.x;
    int w = t >> 6;               // wave 0..3
    int lane = t & 63;
    int q = lane >> 4, n = lane & 15;
    int gc = 16 * w + n;          // this lane's C-layout global column

    __shared__ float tiles[2][3][16 * 68];     // [buf][xq,xk,xv][token][feat] fp32
    __shared__ unsigned short tbq[2][16 * 72]; // bf16 xq tiles
    __shared__ unsigned short tbk[2][16 * 72]; // bf16 xk tiles
    __shared__ float svb[2][16];
    __shared__ unsigned short wt_hi[64 * 72];  // [col][k]
    __shared__ unsigned short wt_lo[64 * 72];
    __shared__ float zTr[16 * 68];             // z1 row-major bounce [token][col]
    __shared__ unsigned short gbufT[64 * 32];  // [col][k] bf16, k>=16 zero
    __shared__ unsigned short sxkT[64 * 32];   // [col][k] bf16, k>=16 zero
    __shared__ unsigned short attb[16 * 32];   // [i][j] bf16, j>=16 zero
    __shared__ float pb[4 * 64];               // b1-partials [wave][col]
    __shared__ float s1p[16 * 4], s2p[16 * 4]; // z1 LN partials [row][wave]
    __shared__ float s1z[16 * 4], s2z[16 * 4]; // zbar LN partials [row][wave]

    // ---- init W1 as hi/lo bf16, transposed ----
    #pragma unroll
    for (int i = 0; i < 16; ++i) {
        int k = i * 4 + w;        // 0..63
        float val = W1in[(size_t)h * 4096 + (size_t)k * 64 + lane];
        unsigned short hi = f2bf(val);
        unsigned short lo = f2bf(val - b2f(hi));
        wt_hi[lane * 72 + k] = hi;
        wt_lo[lane * 72 + k] = lo;
    }
    // ---- zero pads ----
    #pragma unroll
    for (int i = 0; i < 8; ++i) { gbufT[i * 256 + t] = 0; sxkT[i * 256 + t] = 0; }
    #pragma unroll
    for (int i = 0; i < 2; ++i) attb[i * 256 + t] = 0;

    float b1r = b1in[h * 64 + lane];   // lane-indexed (phase B row-major)
    float b1c = b1in[h * 64 + gc];     // gc-indexed (phases A/C/D C-layout)
    float lnwr = lnw_g[h * 64 + lane];
    float lnbr = lnb_g[h * 64 + lane];
    float lnwc = lnw_g[h * 64 + gc];
    float lnbc = lnb_g[h * 64 + gc];

    const size_t gbase = ((size_t)b * Ls) * Dd + h * 64;
    const float* lrp = lrbuf + (size_t)bh * Ls;
    const unsigned short* attp_base = attG + (size_t)bh * NMBc * 256;
    int arow = 4 * w + (lane >> 2), ac4 = (lane & 3) * 4;  // attb staging (16 lanes/wave)

    int rowp = t >> 4, c4p = (t & 15) * 4;     // staging pattern: 16 rows x 16 float4
    float4 lnw4 = *(const float4*)(lnw_g + h * 64 + c4p);
    float4 lnb4 = *(const float4*)(lnb_g + h * 64 + c4p);

    // ---- prologue: step 0 staged (+fixup), prefetch step 1 (raw) + att step 0 ----
    {
        float4 q0 = *(const float4*)(XQ + gbase + (size_t)rowp * Dd + c4p);
        float4 k0 = *(const float4*)(XK + gbase + (size_t)rowp * Dd + c4p);
        float4 v0 = *(const float4*)(XV + gbase + (size_t)rowp * Dd + c4p);
        stage_qkv(q0, k0, v0, &tiles[0][0][0], &tiles[0][1][0], &tiles[0][2][0],
                  tbq[0], tbk[0], rowp, c4p, lnw4, lnb4);
    }
    if (t < 16) svb[0][t] = lrp[t];
    float4 preq = *(const float4*)(XQ + gbase + (size_t)(16 + rowp) * Dd + c4p);
    float4 prek = *(const float4*)(XK + gbase + (size_t)(16 + rowp) * Dd + c4p);
    float4 prev = *(const float4*)(XV + gbase + (size_t)(16 + rowp) * Dd + c4p);
    float presv = (t < 16) ? lrp[16 + t] : 0.f;
    ushort4 attp = {0, 0, 0, 0};
    if (lane < 16) attp = *(const ushort4*)(attp_base + arow * 16 + ac4); // step 0
    __syncthreads();

    const f32x4 zero4 = {0.f, 0.f, 0.f, 0.f};

    for (int nmb = 0; nmb < NMBc; ++nmb) {
        int cb = nmb & 1, nb2 = cb ^ 1;
        int l0 = nmb * 16;
        // ---- stage step n+1 (+fused fixup); attb for CURRENT step; prefetch n+2 ----
        stage_qkv(preq, prek, prev, &tiles[nb2][0][0], &tiles[nb2][1][0], &tiles[nb2][2][0],
                  tbq[nb2], tbk[nb2], rowp, c4p, lnw4, lnb4);
        if (t < 16) svb[nb2][t] = presv;
        if (lane < 16) {
            *(ushort4*)&attb[arow * 32 + ac4] = attp;  // ordered vs prev step's read by B3
            int ap = (nmb + 1 < NMBc) ? (nmb + 1) : (NMBc - 1);
            attp = *(const ushort4*)(attp_base + (size_t)ap * 256 + arow * 16 + ac4);
        }
        int lp = (l0 + 32 <= Ls - 16) ? (l0 + 32) : (Ls - 16);
        preq = *(const float4*)(XQ + gbase + (size_t)(lp + rowp) * Dd + c4p);
        prek = *(const float4*)(XK + gbase + (size_t)(lp + rowp) * Dd + c4p);
        prev = *(const float4*)(XV + gbase + (size_t)(lp + rowp) * Dd + c4p);
        presv = (t < 16) ? lrp[lp + t] : 0.f;

        const float* xqs = &tiles[cb][0][0];
        const float* xks = &tiles[cb][1][0];
        const float* xvs = &tiles[cb][2][0];
        const unsigned short* bqs = tbq[cb];
        const unsigned short* bks = tbk[cb];

        // ---- xq/xk A-frags: direct b128 reads from bf16 tiles ----
        bf16x8 qf0 = *(const bf16x8*)&bqs[n * 72 + 8 * q];
        bf16x8 qf1 = *(const bf16x8*)&bqs[n * 72 + 32 + 8 * q];
        bf16x8 kf0 = *(const bf16x8*)&bks[n * 72 + 8 * q];
        bf16x8 kf1 = *(const bf16x8*)&bks[n * 72 + 32 + 8 * q];

        // ---- W1 B-frags (own slab) ----
        bf16x8 wh0 = *(const bf16x8*)&wt_hi[gc * 72 + 8 * q];
        bf16x8 wh1 = *(const bf16x8*)&wt_hi[gc * 72 + 32 + 8 * q];
        bf16x8 wl0 = *(const bf16x8*)&wt_lo[gc * 72 + 8 * q];
        bf16x8 wl1 = *(const bf16x8*)&wt_lo[gc * 72 + 32 + 8 * q];

        // ---- MFMAs: Z1 slab, Zbar partial (hi/lo split, depth 2) ----
        f32x4 z1 = __builtin_amdgcn_mfma_f32_16x16x32_bf16(kf0, wh0, zero4, 0, 0, 0);
        z1 = __builtin_amdgcn_mfma_f32_16x16x32_bf16(kf1, wh1, z1, 0, 0, 0);
        f32x4 z1l = __builtin_amdgcn_mfma_f32_16x16x32_bf16(kf0, wl0, zero4, 0, 0, 0);
        z1l = __builtin_amdgcn_mfma_f32_16x16x32_bf16(kf1, wl1, z1l, 0, 0, 0);
        z1 = z1 + z1l;
        f32x4 zb = __builtin_amdgcn_mfma_f32_16x16x32_bf16(qf0, wh0, zero4, 0, 0, 0);
        zb = __builtin_amdgcn_mfma_f32_16x16x32_bf16(qf1, wh1, zb, 0, 0, 0);
        f32x4 zbl = __builtin_amdgcn_mfma_f32_16x16x32_bf16(qf0, wl0, zero4, 0, 0, 0);
        zbl = __builtin_amdgcn_mfma_f32_16x16x32_bf16(qf1, wl1, zbl, 0, 0, 0);
        zb = zb + zbl;

        // ---- bounce Z1 row-major (conflict-free scalar writes) ----
        #pragma unroll
        for (int r = 0; r < 4; ++r) zTr[(4 * q + r) * 68 + gc] = z1[r];
        // ---- C-layout s1/s2 partials of zar = z1 + b1c (hides under MFMAs) ----
        {
            float p1[4], p2[4];
            #pragma unroll
            for (int r = 0; r < 4; ++r) {
                float za = z1[r] + b1c;
                p1[r] = rsum16(za);
                p2[r] = rsum16(za * za);
            }
            if (n < 4) {
                s1p[(4 * q + n) * 4 + w] = sel4(n, p1[0], p1[1], p1[2], p1[3]);
                s2p[(4 * q + n) * 4 + w] = sel4(n, p2[0], p2[1], p2[2], p2[3]);
            }
        }
        __syncthreads(); // B1

        // ======== row-major grad phase: lane = col, rows 4w+r ========
        float xk_rm[4], xv_rm[4], zar[4];
        #pragma unroll
        for (int r = 0; r < 4; ++r) {
            int rw = 4 * w + r;
            zar[r] = zTr[rw * 68 + lane] + b1r;
            xk_rm[r] = xks[rw * 68 + lane];
            xv_rm[r] = xvs[rw * 68 + lane];
        }
        float4 svr4 = *(const float4*)&svb[cb][4 * w];
        float svr[4] = {svr4.x, svr4.y, svr4.z, svr4.w};
        float gr[4]; float pbv = 0.f;
        #pragma unroll
        for (int r = 0; r < 4; ++r) {
            int rw = 4 * w + r;
            float4 a1 = *(const float4*)&s1p[rw * 4];
            float4 a2 = *(const float4*)&s2p[rw * 4];
            float s1 = a1.x + a1.y + a1.z + a1.w;
            float s2 = a2.x + a2.y + a2.z + a2.w;
            float mu = s1 * (1.f / 64.f);
            float var = s2 * (1.f / 64.f) - mu * mu;
            float rstd = rsqrtf(var + 1e-6f);
            float xh = (zar[r] - mu) * rstd;
            float g = (lnwr * xh + lnbr - (xv_rm[r] - xk_rm[r])) * lnwr;
            float sg = wsum64(g);
            float sxg = wsum64(xh * g);
            gr[r] = (64.f * g - sg - xh * sxg) * rstd * (1.f / 64.f);
            pbv += svr[r] * gr[r];
        }
        {
            ushort4 gp, sp;
            gp.x = f2bf(gr[0]); gp.y = f2bf(gr[1]); gp.z = f2bf(gr[2]); gp.w = f2bf(gr[3]);
            sp.x = f2bf(svr[0] * xk_rm[0]); sp.y = f2bf(svr[1] * xk_rm[1]);
            sp.z = f2bf(svr[2] * xk_rm[2]); sp.w = f2bf(svr[3] * xk_rm[3]);
            *(ushort4*)&gbufT[lane * 32 + 4 * w] = gp;
            *(ushort4*)&sxkT[lane * 32 + 4 * w] = sp;
            pb[w * 64 + lane] = pbv;
        }
        __syncthreads(); // B2

        // ======== phase C: zb finish, zbar partials, W1 update, b1 updates ========
        bf16x8 gF = *(const bf16x8*)&gbufT[gc * 32 + 8 * q];
        bf16x8 amF = *(const bf16x8*)&attb[n * 32 + 8 * q];
        zb = __builtin_amdgcn_mfma_f32_16x16x32_bf16(amF, gF, zb, 0, 0, 0);
        float zbar[4], xqc[4];
        {
            float pz1[4], pz2[4];
            #pragma unroll
            for (int r = 0; r < 4; ++r) {
                zbar[r] = zb[r] + b1c;        // old b1c
                pz1[r] = rsum16(zbar[r]);
                pz2[r] = rsum16(zbar[r] * zbar[r]);
                xqc[r] = xqs[(4 * q + r) * 68 + gc];   // carry xq (pre-B3: buffer reuse safety)
            }
            if (n < 4) {
                s1z[(4 * q + n) * 4 + w] = sel4(n, pz1[0], pz1[1], pz1[2], pz1[3]);
                s2z[(4 * q + n) * 4 + w] = sel4(n, pz2[0], pz2[1], pz2[2], pz2[3]);
            }
        }
        // ---- W1 update: own slab -= (sv.xk)^T @ grad ----
        #pragma unroll
        for (int tm = 0; tm < 4; ++tm) {
            bf16x8 ax = *(const bf16x8*)&sxkT[(16 * tm + n) * 32 + 8 * q];
            f32x4 dl = __builtin_amdgcn_mfma_f32_16x16x32_bf16(ax, gF, zero4, 0, 0, 0);
            int ko = 16 * tm + 4 * q;
            ushort4 h4 = *(ushort4*)&wt_hi[gc * 72 + ko];
            ushort4 l4 = *(ushort4*)&wt_lo[gc * 72 + ko];
            float w0 = b2f(h4.x) + b2f(l4.x) - dl[0];
            float w1 = b2f(h4.y) + b2f(l4.y) - dl[1];
            float w2 = b2f(h4.z) + b2f(l4.z) - dl[2];
            float w3 = b2f(h4.w) + b2f(l4.w) - dl[3];
            h4.x = f2bf(w0); l4.x = f2bf(w0 - b2f(h4.x));
            h4.y = f2bf(w1); l4.y = f2bf(w1 - b2f(h4.y));
            h4.z = f2bf(w2); l4.z = f2bf(w2 - b2f(h4.z));
            h4.w = f2bf(w3); l4.w = f2bf(w3 - b2f(h4.w));
            *(ushort4*)&wt_hi[gc * 72 + ko] = h4;
            *(ushort4*)&wt_lo[gc * 72 + ko] = l4;
        }
        // ---- b1 updates (old values used above) ----
        float b1r_n = b1r - (pb[0 * 64 + lane] + pb[64 + lane] +
                             pb[128 + lane] + pb[192 + lane]);
        float b1c_n = b1c - (pb[0 * 64 + gc] + pb[64 + gc] +
                             pb[128 + gc] + pb[192 + gc]);
        __syncthreads(); // B3

        // ======== phase D: zbar LN from partials + output (C-layout) ========
        #pragma unroll
        for (int r = 0; r < 4; ++r) {
            int row = 4 * q + r;
            float4 a1 = *(const float4*)&s1z[row * 4];
            float4 a2 = *(const float4*)&s2z[row * 4];
            float s1 = a1.x + a1.y + a1.z + a1.w;
            float s2 = a2.x + a2.y + a2.z + a2.w;
            float mu = s1 * (1.f / 64.f);
            float var = s2 * (1.f / 64.f) - mu * mu;
            float rstd = rsqrtf(var + 1e-6f);
            float o = lnwc * ((zbar[r] - mu) * rstd) + lnbc + xqc[r];
            Y[gbase + (size_t)(l0 + row) * Dd + gc] = o;
        }
        b1r = b1r_n; b1c = b1c_n;
    }
}

// ---------------- post layernorm over D + cast to bf16 ----------------
__global__ __launch_bounds__(256) void postnorm_kernel(const float* __restrict__ Y,
                                                       const float* __restrict__ pw,
                                                       const float* __restrict__ pb,
                                                       unsigned short* __restrict__ Yb) {
    int tok = blockIdx.x, t = threadIdx.x;
    const float* row = Y + (size_t)tok * Dd;
    int c0 = t * 4, c1 = 1024 + t * 4;
    float4 v0 = *(const float4*)(row + c0);
    float4 v1 = *(const float4*)(row + c1);
    float s1 = v0.x + v0.y + v0.z + v0.w + v1.x + v1.y + v1.z + v1.w;
    float s2 = v0.x * v0.x + v0.y * v0.y + v0.z * v0.z + v0.w * v0.w +
               v1.x * v1.x + v1.y * v1.y + v1.z * v1.z + v1.w * v1.w;
    s1 = wsum64(s1); s2 = wsum64(s2);
    __shared__ float r1[4], r2[4];
    if ((t & 63) == 0) { r1[t >> 6] = s1; r2[t >> 6] = s2; }
    __syncthreads();
    float S1 = r1[0] + r1[1] + r1[2] + r1[3];
    float S2 = r2[0] + r2[1] + r2[2] + r2[3];
    float mu = S1 * (1.f / 2048.f);
    float var = S2 * (1.f / 2048.f) - mu * mu;
    float rstd = rsqrtf(var + 1e-6f);
    float4 w0 = *(const float4*)(pw + c0), b0 = *(const float4*)(pb + c0);
    float4 w1 = *(const float4*)(pw + c1), b1 = *(const float4*)(pb + c1);
    ushort4 o0, o1;
    o0.x = f2bf((v0.x - mu) * rstd * w0.x + b0.x);
    o0.y = f2bf((v0.y - mu) * rstd * w0.y + b0.y);
    o0.z = f2bf((v0.z - mu) * rstd * w0.z + b0.z);
    o0.w = f2bf((v0.w - mu) * rstd * w0.w + b0.w);
    o1.x = f2bf((v1.x - mu) * rstd * w1.x + b1.x);
    o1.y = f2bf((v1.y - mu) * rstd * w1.y + b1.y);
    o1.z = f2bf((v1.z - mu) * rstd * w1.z + b1.z);
    o1.w = f2bf((v1.w - mu) * rstd * w1.w + b1.w);
    *(ushort4*)(Yb + (size_t)tok * Dd + c0) = o0;
    *(ushort4*)(Yb + (size_t)tok * Dd + c1) = o1;
}

extern "C" void kernel_launch(void* const* d_in, const int* in_sizes, int n_in,
                              void* d_out, int out_size, void* d_ws, size_t ws_size,
                              hipStream_t stream) {
    const float* hs   = (const float*)d_in[0];
    const float* wq_w = (const float*)d_in[1];
    const float* wq_b = (const float*)d_in[2];
    const float* wk_w = (const float*)d_in[3];
    const float* wk_b = (const float*)d_in[4];
    const float* wv_w = (const float*)d_in[5];
    const float* wv_b = (const float*)d_in[6];
    const float* wo_w = (const float*)d_in[7];
    const float* wo_b = (const float*)d_in[8];
    const float* lnw  = (const float*)d_in[9];
    const float* lnb  = (const float*)d_in[10];
    const float* lr_w = (const float*)d_in[11];
    const float* lr_b = (const float*)d_in[12];
    const float* W1   = (const float*)d_in[13];
    const float* b1   = (const float*)d_in[14];
    const float* pnw  = (const float*)d_in[15];
    const float* pnb  = (const float*)d_in[16];
    float* out = (float*)d_out;

    char* ws = (char*)d_ws;
    size_t off = 0;
    auto alloc = [&](size_t bytes) -> void* {
        void* p = ws + off; off += (bytes + 255) & ~(size_t)255; return p;
    };
    unsigned short* hsb = (unsigned short*)alloc((size_t)MTOK * Dd * 2);
    unsigned short* wtb = (unsigned short*)alloc((size_t)Dd * Dd * 2);
    float* XQ = (float*)alloc((size_t)MTOK * Dd * 4);
    float* XK = (float*)alloc((size_t)MTOK * Dd * 4);
    float* XV = (float*)alloc((size_t)MTOK * Dd * 4);
    float* lrbuf = (float*)alloc((size_t)Bb * Hh * Ls * 4);
    float* Y = XQ;                 // safe alias (per-chain row/col ownership; writes trail reads)
    unsigned short* Yb = hsb;      // hsb dead after QKV GEMMs
    // attG (8.4 MB) aliases hsb: hsb (as bf16 hs) is dead after the QKV GEMMs;
    // attG is dead before postnorm writes Yb over it. Stream-ordered, no overlap.
    unsigned short* attG = hsb;

    dim3 blk(256);
    cast_hs_kernel<<<dim3(MTOK * Dd / 1024), blk, 0, stream>>>(hs, hsb);

    transpose_cast_kernel<<<dim3(1024), blk, 0, stream>>>(wq_w, wtb);
    gemm_bt_kernel<<<dim3(64, 16), blk, 0, stream>>>(hsb, wtb, wq_b, XQ, MTOK, Dd, Dd);
    transpose_cast_kernel<<<dim3(1024), blk, 0, stream>>>(wk_w, wtb);
    gemm_bt_kernel<<<dim3(64, 16), blk, 0, stream>>>(hsb, wtb, wk_b, XK, MTOK, Dd, Dd);
    transpose_cast_kernel<<<dim3(1024), blk, 0, stream>>>(wv_w, wtb);
    gemm_bt_kernel<<<dim3(64, 16), blk, 0, stream>>>(hsb, wtb, wv_b, XV, MTOK, Dd, Dd);

    lr_kernel<<<dim3(MTOK), blk, 0, stream>>>(hs, lr_w, lr_b, lrbuf);
    attn_kernel<<<dim3(Bb * Hh * NMBc / 4), blk, 0, stream>>>(XQ, XK, lrbuf, attG);

    scan_kernel<<<dim3(Bb * Hh), blk, 0, stream>>>(XQ, XK, XV, lrbuf, attG, W1, b1, lnw, lnb, Y);

    postnorm_kernel<<<dim3(MTOK), blk, 0, stream>>>(Y, pnw, pnb, Yb);

    transpose_cast_kernel<<<dim3(1024), blk, 0, stream>>>(wo_w, wtb);
    gemm_bt_kernel<<<dim3(64, 16), blk, 0, stream>>>(Yb, wtb, wo_b, out, MTOK, Dd, Dd);
}

// Round 5
// 1434.078 us; speedup vs baseline: 1.0094x; 1.0094x over previous
//
#include <hip/hip_runtime.h>
#include <hip/hip_bf16.h>
#include <cstdint>
#include <cstddef>

#define DEV __device__ __forceinline__

constexpr int Bb = 2, Ls = 4096, Dd = 2048, Hh = 32, HD = 64, MBK = 16, NMBc = 256;
constexpr int MTOK = Bb * Ls; // 8192 tokens

typedef __bf16 bf16x8 __attribute__((ext_vector_type(8)));
typedef float  f32x4  __attribute__((ext_vector_type(4)));

// hardware RNE f32->bf16
DEV unsigned short f2bf(float f) {
    union { __bf16 h; unsigned short u; } x;
    x.h = (__bf16)f;
    return x.u;
}
DEV float b2f(unsigned short u) {
    union { unsigned int i; float f; } x; x.i = ((unsigned int)u) << 16;
    return x.f;
}

// 64-lane sum via DPP; lane 63 holds total, readlane broadcasts (uniform use).
DEV float wsum64(float v) {
    int t;
    t = __builtin_amdgcn_update_dpp(0, __float_as_int(v), 0x111, 0xf, 0xf, true); v += __int_as_float(t);
    t = __builtin_amdgcn_update_dpp(0, __float_as_int(v), 0x112, 0xf, 0xf, true); v += __int_as_float(t);
    t = __builtin_amdgcn_update_dpp(0, __float_as_int(v), 0x114, 0xf, 0xf, true); v += __int_as_float(t);
    t = __builtin_amdgcn_update_dpp(0, __float_as_int(v), 0x118, 0xf, 0xf, true); v += __int_as_float(t);
    t = __builtin_amdgcn_update_dpp(0, __float_as_int(v), 0x142, 0xa, 0xf, true); v += __int_as_float(t);
    t = __builtin_amdgcn_update_dpp(0, __float_as_int(v), 0x143, 0xc, 0xf, true); v += __int_as_float(t);
    return __int_as_float(__builtin_amdgcn_readlane(__float_as_int(v), 63));
}

// 16-lane (DPP row) rotate-reduce sum: every lane of each row-of-16 gets the row total.
DEV float rsum16(float v) {
    int t;
    t = __builtin_amdgcn_update_dpp(0, __float_as_int(v), 0x121, 0xf, 0xf, true); v += __int_as_float(t); // ror1
    t = __builtin_amdgcn_update_dpp(0, __float_as_int(v), 0x122, 0xf, 0xf, true); v += __int_as_float(t); // ror2
    t = __builtin_amdgcn_update_dpp(0, __float_as_int(v), 0x124, 0xf, 0xf, true); v += __int_as_float(t); // ror4
    t = __builtin_amdgcn_update_dpp(0, __float_as_int(v), 0x128, 0xf, 0xf, true); v += __int_as_float(t); // ror8
    return v;
}

// runtime-n select from 4 scalars (no dynamic indexing -> no scratch)
DEV float sel4(int n, float a, float b, float c, float d) {
    float v = (n == 1) ? b : a;
    v = (n == 2) ? c : v;
    v = (n == 3) ? d : v;
    return v;
}

DEV void g2l16(const void* g, void* l) {
    __builtin_amdgcn_global_load_lds(
        (__attribute__((address_space(1))) void*)(g),
        (__attribute__((address_space(3))) void*)(l), 16, 0, 0);
}

// ---------------- cast hidden_states fp32 -> bf16 ----------------
__global__ __launch_bounds__(256) void cast_hs_kernel(const float* __restrict__ src,
                                                      unsigned short* __restrict__ dst) {
    int i = (blockIdx.x * 256 + threadIdx.x) * 4;
    float4 v = *(const float4*)(src + i);
    ushort4 o; o.x = f2bf(v.x); o.y = f2bf(v.y); o.z = f2bf(v.z); o.w = f2bf(v.w);
    *(ushort4*)(dst + i) = o;
}

// ---------------- transpose + cast weight: W[k][n] fp32 -> Wt[n][k] bf16 ----------------
__global__ __launch_bounds__(256) void transpose_cast_kernel(const float* __restrict__ W,
                                                             unsigned short* __restrict__ Wt) {
    __shared__ float tile[64][65];
    int bx = blockIdx.x & 31;   // k-tile
    int by = blockIdx.x >> 5;   // n-tile
    int t = threadIdx.x;
    int r = t >> 4, c4 = (t & 15) * 4;
    #pragma unroll
    for (int i = 0; i < 4; ++i) {
        int row = r + i * 16;
        float4 v = *(const float4*)(W + (size_t)(bx * 64 + row) * Dd + by * 64 + c4);
        tile[row][c4 + 0] = v.x; tile[row][c4 + 1] = v.y;
        tile[row][c4 + 2] = v.z; tile[row][c4 + 3] = v.w;
    }
    __syncthreads();
    #pragma unroll
    for (int i = 0; i < 4; ++i) {
        int row = r + i * 16; // n index
        ushort4 o;
        o.x = f2bf(tile[c4 + 0][row]); o.y = f2bf(tile[c4 + 1][row]);
        o.z = f2bf(tile[c4 + 2][row]); o.w = f2bf(tile[c4 + 3][row]);
        *(ushort4*)(Wt + (size_t)(by * 64 + row) * Dd + bx * 64 + c4) = o;
    }
}

// ---------------- bf16 MFMA GEMM:  C[M,N] = A[M,K] @ Bt[N,K]^T + bias ----------------
__global__ __launch_bounds__(256) void gemm_bt_kernel(const unsigned short* __restrict__ A,
                                                      const unsigned short* __restrict__ Bt,
                                                      const float* __restrict__ bias,
                                                      float* __restrict__ C,
                                                      int M, int N, int Kd) {
    __shared__ unsigned short sA[128 * 64];
    __shared__ unsigned short sB[128 * 64];
    int t = threadIdx.x;
    int lane = t & 63;
    int wid = t >> 6, wm = wid >> 1, wn = wid & 1;
    int quad = lane >> 4, c = lane & 15;
    int bm = blockIdx.x, bn = blockIdx.y;

    const unsigned short* pa[4]; const unsigned short* pb[4];
    unsigned short* la[4]; unsigned short* lb[4];
    #pragma unroll
    for (int i = 0; i < 4; ++i) {
        int lin = i * 256 + t;
        int row = lin >> 3, blk = lin & 7;
        int oct = blk ^ (row & 7);
        pa[i] = A  + (size_t)(bm * 128 + row) * Kd + oct * 8;
        pb[i] = Bt + (size_t)(bn * 128 + row) * Kd + oct * 8;
        la[i] = sA + lin * 8;
        lb[i] = sB + lin * 8;
    }

    f32x4 acc[4][4];
    #pragma unroll
    for (int i = 0; i < 4; ++i)
        #pragma unroll
        for (int j = 0; j < 4; ++j)
            #pragma unroll
            for (int r = 0; r < 4; ++r) acc[i][j][r] = 0.f;

    const char* sAc = (const char*)sA;
    const char* sBc = (const char*)sB;
    int rowA0 = wm * 64 + c, rowB0 = wn * 64 + c;
    int sw = (c & 7);

    int nkt = Kd >> 6;
    for (int kt = 0; kt < nkt; ++kt) {
        #pragma unroll
        for (int i = 0; i < 4; ++i) {
            g2l16(pa[i], la[i]);
            g2l16(pb[i], lb[i]);
            pa[i] += 64; pb[i] += 64;
        }
        __syncthreads();
        #pragma unroll
        for (int s = 0; s < 2; ++s) {
            bf16x8 af[4], bfv[4];
            int so = (s << 2) | quad;
            #pragma unroll
            for (int mt = 0; mt < 4; ++mt)
                af[mt] = *(const bf16x8*)(sAc + (rowA0 + mt * 16) * 128 + ((so ^ sw) * 16));
            #pragma unroll
            for (int nt = 0; nt < 4; ++nt)
                bfv[nt] = *(const bf16x8*)(sBc + (rowB0 + nt * 16) * 128 + ((so ^ sw) * 16));
            #pragma unroll
            for (int mt = 0; mt < 4; ++mt)
                #pragma unroll
                for (int nt = 0; nt < 4; ++nt)
                    acc[mt][nt] = __builtin_amdgcn_mfma_f32_16x16x32_bf16(af[mt], bfv[nt], acc[mt][nt], 0, 0, 0);
        }
        __syncthreads();
    }

    float bv[4];
    #pragma unroll
    for (int nt = 0; nt < 4; ++nt) bv[nt] = bias[bn * 128 + wn * 64 + nt * 16 + c];
    #pragma unroll
    for (int mt = 0; mt < 4; ++mt)
        #pragma unroll
        for (int r = 0; r < 4; ++r) {
            int row = bm * 128 + wm * 64 + mt * 16 + quad * 4 + r;
            float* cp = C + (size_t)row * N + bn * 128 + wn * 64 + c;
            #pragma unroll
            for (int nt = 0; nt < 4; ++nt) cp[nt * 16] = acc[mt][nt][r] + bv[nt];
        }
}

// ---------------- lr: s[b,h,l] = sigmoid(hs[b,l,:]·lr_w[h,:] + lr_b[h]) / (HD*K) ----------------
__global__ __launch_bounds__(256) void lr_kernel(const float* __restrict__ hs,
                                                 const float* __restrict__ lrw,
                                                 const float* __restrict__ lrb,
                                                 float* __restrict__ lr_out) {
    int tok = blockIdx.x; // b*L + l
    int t = threadIdx.x;
    int h = t >> 3, j0 = t & 7;
    const float* row = hs + (size_t)tok * Dd;
    const float* wr = lrw + (size_t)h * Dd;
    float p = 0.f;
    for (int j = j0 * 4; j < Dd; j += 32) {
        float4 a = *(const float4*)(row + j);
        float4 w = *(const float4*)(wr + j);
        p += a.x * w.x + a.y * w.y + a.z * w.z + a.w * w.w;
    }
    __shared__ float red[32][8];
    red[h][j0] = p;
    __syncthreads();
    if (t < 32) {
        float s = 0.f;
        #pragma unroll
        for (int i = 0; i < 8; ++i) s += red[t][i];
        s += lrb[t];
        s = 1.f / (1.f + expf(-s));
        s *= 1.0f / (HD * MBK);
        int b = tok >> 12, l = tok & (Ls - 1);
        lr_out[(size_t)(b * Hh + t) * Ls + l] = s;
    }
}

// staging-time fixup: L2-normalize q,k; v <- ln(v-k)+k. Row = 16 lanes x float4.
DEV void stage_qkv(float4 q, float4 k, float4 v,
                   float* tq, float* tk, float* tv,
                   unsigned short* bq, unsigned short* bk,
                   int rowp, int c4p, float4 lnw4, float4 lnb4) {
    float rq = 1.f / fmaxf(sqrtf(rsum16(q.x*q.x + q.y*q.y + q.z*q.z + q.w*q.w)), 1e-12f);
    q.x *= rq; q.y *= rq; q.z *= rq; q.w *= rq;
    float rk = 1.f / fmaxf(sqrtf(rsum16(k.x*k.x + k.y*k.y + k.z*k.z + k.w*k.w)), 1e-12f);
    k.x *= rk; k.y *= rk; k.z *= rk; k.w *= rk;
    float4 df; df.x = v.x - k.x; df.y = v.y - k.y; df.z = v.z - k.z; df.w = v.w - k.w;
    float mu = rsum16(df.x + df.y + df.z + df.w) * (1.f / 64.f);
    float4 cc; cc.x = df.x - mu; cc.y = df.y - mu; cc.z = df.z - mu; cc.w = df.w - mu;
    float var = rsum16(cc.x*cc.x + cc.y*cc.y + cc.z*cc.z + cc.w*cc.w) * (1.f / 63.f); // ddof=1
    float rs = 1.f / (sqrtf(var) + 1e-8f);
    float4 vn;
    vn.x = lnw4.x * cc.x * rs + lnb4.x + k.x;
    vn.y = lnw4.y * cc.y * rs + lnb4.y + k.y;
    vn.z = lnw4.z * cc.z * rs + lnb4.z + k.z;
    vn.w = lnw4.w * cc.w * rs + lnb4.w + k.w;
    *(float4*)&tq[rowp * 68 + c4p] = q;
    *(float4*)&tk[rowp * 68 + c4p] = k;
    *(float4*)&tv[rowp * 68 + c4p] = vn;
    ushort4 qb, kb;
    qb.x = f2bf(q.x); qb.y = f2bf(q.y); qb.z = f2bf(q.z); qb.w = f2bf(q.w);
    kb.x = f2bf(k.x); kb.y = f2bf(k.y); kb.z = f2bf(k.z); kb.w = f2bf(k.w);
    *(ushort4*)&bq[rowp * 72 + c4p] = qb;
    *(ushort4*)&bk[rowp * 72 + c4p] = kb;
}

// ---------------- MFMA TTT scan: 4 waves per (b,h) chain ----------------
// 2-barrier pipelined schedule:
//   top:  stage tile n+1 from prefetch regs (+fused fixup)
//   A:    frags + z1/zb MFMAs + zTr bounce + z1-LN partials + wave0 attn->attb[cb]
//   B1
//   B-region: deferred phase-D of step n-1 (zbar LN + Y store, regs+s1z/s2z),
//             then grad phase (row-major) -> gbufT/sxkT/pb; xqc read here (pre-B2)
//   B2
//   C-region: ISSUE prefetch loads (tile n+2; no barrier until consumption),
//             zb finish + zbar + LN partials + W1 update + b1 updates; carry regs
// All cross-step LDS hazards ordered by B1/B2 (wt is wave-private: no barrier).
__global__ __launch_bounds__(256, 1) void scan_kernel(const float* __restrict__ XQ,
                                                      const float* __restrict__ XK,
                                                      const float* __restrict__ XV,
                                                      const float* __restrict__ lrbuf,
                                                      const float* __restrict__ W1in,
                                                      const float* __restrict__ b1in,
                                                      const float* __restrict__ lnw_g,
                                                      const float* __restrict__ lnb_g,
                                                      float* __restrict__ Y) {
    int bh = blockIdx.x;          // b*H + h
    int b = bh >> 5, h = bh & 31;
    int t = threadIdx.x;
    int w = t >> 6;               // wave 0..3
    int lane = t & 63;
    int q = lane >> 4, n = lane & 15;
    int gc = 16 * w + n;          // this lane's C-layout global column

    __shared__ float tiles[2][3][16 * 68];     // [buf][xq,xk,xv][token][feat] fp32
    __shared__ unsigned short tbq[2][16 * 72]; // bf16 xq tiles
    __shared__ unsigned short tbk[2][16 * 72]; // bf16 xk tiles
    __shared__ float svb[2][16];
    __shared__ unsigned short wt_hi[64 * 72];  // [col][k]
    __shared__ unsigned short wt_lo[64 * 72];
    __shared__ float zTr[16 * 68];             // z1 row-major bounce [token][col]
    __shared__ unsigned short gbufT[64 * 32];  // [col][k] bf16, k>=16 zero
    __shared__ unsigned short sxkT[64 * 32];   // [col][k] bf16, k>=16 zero
    __shared__ unsigned short attb[2][16 * 32];// [buf][i][j] bf16, j>=16 zero
    __shared__ float pb[4 * 64];               // b1-partials [wave][col]
    __shared__ float s1p[16 * 4], s2p[16 * 4]; // z1 LN partials [row][wave]
    __shared__ float s1z[16 * 4], s2z[16 * 4]; // zbar LN partials [row][wave]

    // ---- init W1 as hi/lo bf16, transposed ----
    #pragma unroll
    for (int i = 0; i < 16; ++i) {
        int k = i * 4 + w;        // 0..63
        float val = W1in[(size_t)h * 4096 + (size_t)k * 64 + lane];
        unsigned short hi = f2bf(val);
        unsigned short lo = f2bf(val - b2f(hi));
        wt_hi[lane * 72 + k] = hi;
        wt_lo[lane * 72 + k] = lo;
    }
    // ---- zero pads ----
    #pragma unroll
    for (int i = 0; i < 8; ++i) { gbufT[i * 256 + t] = 0; sxkT[i * 256 + t] = 0; }
    #pragma unroll
    for (int i = 0; i < 4; ++i) attb[0][0] , ((unsigned short*)attb)[i * 256 + t] = 0;

    float b1r = b1in[h * 64 + lane];   // lane-indexed (phase B row-major)
    float b1c = b1in[h * 64 + gc];     // gc-indexed (phases A/C/D C-layout)
    float lnwr = lnw_g[h * 64 + lane];
    float lnbr = lnb_g[h * 64 + lane];
    float lnwc = lnw_g[h * 64 + gc];
    float lnbc = lnb_g[h * 64 + gc];

    const size_t gbase = ((size_t)b * Ls) * Dd + h * 64;
    const float* lrp = lrbuf + (size_t)bh * Ls;

    int rowp = t >> 4, c4p = (t & 15) * 4;     // staging pattern: 16 rows x 16 float4
    float4 lnw4 = *(const float4*)(lnw_g + h * 64 + c4p);
    float4 lnb4 = *(const float4*)(lnb_g + h * 64 + c4p);

    // ---- prologue: step 0 staged (+fixup), prefetch step 1 (raw) ----
    {
        float4 q0 = *(const float4*)(XQ + gbase + (size_t)rowp * Dd + c4p);
        float4 k0 = *(const float4*)(XK + gbase + (size_t)rowp * Dd + c4p);
        float4 v0 = *(const float4*)(XV + gbase + (size_t)rowp * Dd + c4p);
        stage_qkv(q0, k0, v0, &tiles[0][0][0], &tiles[0][1][0], &tiles[0][2][0],
                  tbq[0], tbk[0], rowp, c4p, lnw4, lnb4);
    }
    if (t < 16) svb[0][t] = lrp[t];
    float4 preq = *(const float4*)(XQ + gbase + (size_t)(16 + rowp) * Dd + c4p);
    float4 prek = *(const float4*)(XK + gbase + (size_t)(16 + rowp) * Dd + c4p);
    float4 prev = *(const float4*)(XV + gbase + (size_t)(16 + rowp) * Dd + c4p);
    float presv = (t < 16) ? lrp[16 + t] : 0.f;
    __syncthreads();

    const f32x4 zero4 = {0.f, 0.f, 0.f, 0.f};
    float zbar_p[4] = {0.f, 0.f, 0.f, 0.f};   // deferred-D carries
    float xqc_p[4]  = {0.f, 0.f, 0.f, 0.f};

    for (int nmb = 0; nmb < NMBc; ++nmb) {
        int cb = nmb & 1, nb2 = cb ^ 1;
        int l0 = nmb * 16;
        // ---- top: stage step n+1 from prefetch regs (+fused fixup) ----
        stage_qkv(preq, prek, prev, &tiles[nb2][0][0], &tiles[nb2][1][0], &tiles[nb2][2][0],
                  tbq[nb2], tbk[nb2], rowp, c4p, lnw4, lnb4);
        if (t < 16) svb[nb2][t] = presv;

        const float* xqs = &tiles[cb][0][0];
        const float* xks = &tiles[cb][1][0];
        const float* xvs = &tiles[cb][2][0];
        const unsigned short* bqs = tbq[cb];
        const unsigned short* bks = tbk[cb];

        // ---- xq/xk A-frags: direct b128 reads from bf16 tiles ----
        bf16x8 qf0 = *(const bf16x8*)&bqs[n * 72 + 8 * q];
        bf16x8 qf1 = *(const bf16x8*)&bqs[n * 72 + 32 + 8 * q];
        bf16x8 kf0 = *(const bf16x8*)&bks[n * 72 + 8 * q];
        bf16x8 kf1 = *(const bf16x8*)&bks[n * 72 + 32 + 8 * q];

        // ---- W1 B-frags (own slab; wave-private RMW -> no barrier needed) ----
        bf16x8 wh0 = *(const bf16x8*)&wt_hi[gc * 72 + 8 * q];
        bf16x8 wh1 = *(const bf16x8*)&wt_hi[gc * 72 + 32 + 8 * q];
        bf16x8 wl0 = *(const bf16x8*)&wt_lo[gc * 72 + 8 * q];
        bf16x8 wl1 = *(const bf16x8*)&wt_lo[gc * 72 + 32 + 8 * q];

        // ---- MFMAs: Z1 slab, Zbar partial (hi/lo split, depth 2) ----
        f32x4 z1 = __builtin_amdgcn_mfma_f32_16x16x32_bf16(kf0, wh0, zero4, 0, 0, 0);
        z1 = __builtin_amdgcn_mfma_f32_16x16x32_bf16(kf1, wh1, z1, 0, 0, 0);
        f32x4 z1l = __builtin_amdgcn_mfma_f32_16x16x32_bf16(kf0, wl0, zero4, 0, 0, 0);
        z1l = __builtin_amdgcn_mfma_f32_16x16x32_bf16(kf1, wl1, z1l, 0, 0, 0);
        z1 = z1 + z1l;
        f32x4 zb = __builtin_amdgcn_mfma_f32_16x16x32_bf16(qf0, wh0, zero4, 0, 0, 0);
        zb = __builtin_amdgcn_mfma_f32_16x16x32_bf16(qf1, wh1, zb, 0, 0, 0);
        f32x4 zbl = __builtin_amdgcn_mfma_f32_16x16x32_bf16(qf0, wl0, zero4, 0, 0, 0);
        zbl = __builtin_amdgcn_mfma_f32_16x16x32_bf16(qf1, wl1, zbl, 0, 0, 0);
        zb = zb + zbl;

        // ---- bounce Z1 row-major (conflict-free scalar writes) ----
        #pragma unroll
        for (int r = 0; r < 4; ++r) zTr[(4 * q + r) * 68 + gc] = z1[r];
        // ---- C-layout s1/s2 partials of zar = z1 + b1c ----
        {
            float p1[4], p2[4];
            #pragma unroll
            for (int r = 0; r < 4; ++r) {
                float za = z1[r] + b1c;
                p1[r] = rsum16(za);
                p2[r] = rsum16(za * za);
            }
            if (n < 4) {
                s1p[(4 * q + n) * 4 + w] = sel4(n, p1[0], p1[1], p1[2], p1[3]);
                s2p[(4 * q + n) * 4 + w] = sel4(n, p2[0], p2[1], p2[2], p2[3]);
            }
        }
        // ---- attn + masked -sv_j*(Attn+1) -> attb[cb] (wave 0; parallel MFMA work) ----
        if (w == 0) {
            f32x4 aacc = __builtin_amdgcn_mfma_f32_16x16x32_bf16(qf1, kf1, zero4, 0, 0, 0);
            aacc = __builtin_amdgcn_mfma_f32_16x16x32_bf16(qf0, kf0, aacc, 0, 0, 0);
            float svn = svb[cb][n];
            #pragma unroll
            for (int r = 0; r < 4; ++r) {
                int i = 4 * q + r;
                attb[cb][i * 32 + n] = f2bf((i >= n) ? (-svn * (aacc[r] + 1.f)) : 0.f);
            }
        }
        __syncthreads(); // B1

        // ======== deferred phase D (step n-1): zbar LN + Y store (C-layout) ========
        if (nmb > 0) {
            int l0p = l0 - 16;
            #pragma unroll
            for (int r = 0; r < 4; ++r) {
                int row = 4 * q + r;
                float4 a1 = *(const float4*)&s1z[row * 4];
                float4 a2 = *(const float4*)&s2z[row * 4];
                float s1 = a1.x + a1.y + a1.z + a1.w;
                float s2 = a2.x + a2.y + a2.z + a2.w;
                float mu = s1 * (1.f / 64.f);
                float var = s2 * (1.f / 64.f) - mu * mu;
                float rstd = rsqrtf(var + 1e-6f);
                float o = lnwc * ((zbar_p[r] - mu) * rstd) + lnbc + xqc_p[r];
                Y[gbase + (size_t)(l0p + row) * Dd + gc] = o;
            }
        }

        // ======== row-major grad phase: lane = col, rows 4w+r ========
        float xk_rm[4], xv_rm[4], zar[4], xqc[4];
        #pragma unroll
        for (int r = 0; r < 4; ++r) {
            int rw = 4 * w + r;
            zar[r] = zTr[rw * 68 + lane] + b1r;
            xk_rm[r] = xks[rw * 68 + lane];
            xv_rm[r] = xvs[rw * 68 + lane];
            xqc[r] = xqs[(4 * q + r) * 68 + gc];   // C-layout xq (pre-B2: tile-reuse safety)
        }
        float4 svr4 = *(const float4*)&svb[cb][4 * w];
        float svr[4] = {svr4.x, svr4.y, svr4.z, svr4.w};
        float gr[4]; float pbv = 0.f;
        #pragma unroll
        for (int r = 0; r < 4; ++r) {
            int rw = 4 * w + r;
            float4 a1 = *(const float4*)&s1p[rw * 4];
            float4 a2 = *(const float4*)&s2p[rw * 4];
            float s1 = a1.x + a1.y + a1.z + a1.w;
            float s2 = a2.x + a2.y + a2.z + a2.w;
            float mu = s1 * (1.f / 64.f);
            float var = s2 * (1.f / 64.f) - mu * mu;
            float rstd = rsqrtf(var + 1e-6f);
            float xh = (zar[r] - mu) * rstd;
            float g = (lnwr * xh + lnbr - (xv_rm[r] - xk_rm[r])) * lnwr;
            float sg = wsum64(g);
            float sxg = wsum64(xh * g);
            gr[r] = (64.f * g - sg - xh * sxg) * rstd * (1.f / 64.f);
            pbv += svr[r] * gr[r];
        }
        {
            ushort4 gp, sp;
            gp.x = f2bf(gr[0]); gp.y = f2bf(gr[1]); gp.z = f2bf(gr[2]); gp.w = f2bf(gr[3]);
            sp.x = f2bf(svr[0] * xk_rm[0]); sp.y = f2bf(svr[1] * xk_rm[1]);
            sp.z = f2bf(svr[2] * xk_rm[2]); sp.w = f2bf(svr[3] * xk_rm[3]);
            *(ushort4*)&gbufT[lane * 32 + 4 * w] = gp;
            *(ushort4*)&sxkT[lane * 32 + 4 * w] = sp;
            pb[w * 64 + lane] = pbv;
        }
        __syncthreads(); // B2

        // ======== C-region ========
        // issue prefetch for tile n+2 FIRST: no barrier between here and its
        // consumption at next step's staging -> HBM latency hides under phase C.
        int lp = (l0 + 32 <= Ls - 16) ? (l0 + 32) : (Ls - 16);
        preq = *(const float4*)(XQ + gbase + (size_t)(lp + rowp) * Dd + c4p);
        prek = *(const float4*)(XK + gbase + (size_t)(lp + rowp) * Dd + c4p);
        prev = *(const float4*)(XV + gbase + (size_t)(lp + rowp) * Dd + c4p);
        presv = (t < 16) ? lrp[lp + t] : 0.f;

        bf16x8 gF = *(const bf16x8*)&gbufT[gc * 32 + 8 * q];
        bf16x8 amF = *(const bf16x8*)&attb[cb][n * 32 + 8 * q];
        zb = __builtin_amdgcn_mfma_f32_16x16x32_bf16(amF, gF, zb, 0, 0, 0);
        float zbar[4];
        {
            float pz1[4], pz2[4];
            #pragma unroll
            for (int r = 0; r < 4; ++r) {
                zbar[r] = zb[r] + b1c;        // old b1c
                pz1[r] = rsum16(zbar[r]);
                pz2[r] = rsum16(zbar[r] * zbar[r]);
            }
            if (n < 4) {
                s1z[(4 * q + n) * 4 + w] = sel4(n, pz1[0], pz1[1], pz1[2], pz1[3]);
                s2z[(4 * q + n) * 4 + w] = sel4(n, pz2[0], pz2[1], pz2[2], pz2[3]);
            }
        }
        // ---- W1 update: own slab -= (sv.xk)^T @ grad ----
        #pragma unroll
        for (int tm = 0; tm < 4; ++tm) {
            bf16x8 ax = *(const bf16x8*)&sxkT[(16 * tm + n) * 32 + 8 * q];
            f32x4 dl = __builtin_amdgcn_mfma_f32_16x16x32_bf16(ax, gF, zero4, 0, 0, 0);
            int ko = 16 * tm + 4 * q;
            ushort4 h4 = *(ushort4*)&wt_hi[gc * 72 + ko];
            ushort4 l4 = *(ushort4*)&wt_lo[gc * 72 + ko];
            float w0 = b2f(h4.x) + b2f(l4.x) - dl[0];
            float w1 = b2f(h4.y) + b2f(l4.y) - dl[1];
            float w2 = b2f(h4.z) + b2f(l4.z) - dl[2];
            float w3 = b2f(h4.w) + b2f(l4.w) - dl[3];
            h4.x = f2bf(w0); l4.x = f2bf(w0 - b2f(h4.x));
            h4.y = f2bf(w1); l4.y = f2bf(w1 - b2f(h4.y));
            h4.z = f2bf(w2); l4.z = f2bf(w2 - b2f(h4.z));
            h4.w = f2bf(w3); l4.w = f2bf(w3 - b2f(h4.w));
            *(ushort4*)&wt_hi[gc * 72 + ko] = h4;
            *(ushort4*)&wt_lo[gc * 72 + ko] = l4;
        }
        // ---- b1 updates (old values used above) ----
        float b1r_n = b1r - (pb[0 * 64 + lane] + pb[64 + lane] +
                             pb[128 + lane] + pb[192 + lane]);
        float b1c_n = b1c - (pb[0 * 64 + gc] + pb[64 + gc] +
                             pb[128 + gc] + pb[192 + gc]);
        // ---- carry deferred-D state ----
        #pragma unroll
        for (int r = 0; r < 4; ++r) { zbar_p[r] = zbar[r]; xqc_p[r] = xqc[r]; }
        b1r = b1r_n; b1c = b1c_n;
        // (no B3: next barrier is B1 of step n+1)
    }

    // ---- epilogue: flush deferred phase D for step NMBc-1 ----
    __syncthreads();
    {
        int l0p = (NMBc - 1) * 16;
        #pragma unroll
        for (int r = 0; r < 4; ++r) {
            int row = 4 * q + r;
            float4 a1 = *(const float4*)&s1z[row * 4];
            float4 a2 = *(const float4*)&s2z[row * 4];
            float s1 = a1.x + a1.y + a1.z + a1.w;
            float s2 = a2.x + a2.y + a2.z + a2.w;
            float mu = s1 * (1.f / 64.f);
            float var = s2 * (1.f / 64.f) - mu * mu;
            float rstd = rsqrtf(var + 1e-6f);
            float o = lnwc * ((zbar_p[r] - mu) * rstd) + lnbc + xqc_p[r];
            Y[gbase + (size_t)(l0p + row) * Dd + gc] = o;
        }
    }
}

// ---------------- post layernorm over D + cast to bf16 ----------------
__global__ __launch_bounds__(256) void postnorm_kernel(const float* __restrict__ Y,
                                                       const float* __restrict__ pw,
                                                       const float* __restrict__ pb,
                                                       unsigned short* __restrict__ Yb) {
    int tok = blockIdx.x, t = threadIdx.x;
    const float* row = Y + (size_t)tok * Dd;
    int c0 = t * 4, c1 = 1024 + t * 4;
    float4 v0 = *(const float4*)(row + c0);
    float4 v1 = *(const float4*)(row + c1);
    float s1 = v0.x + v0.y + v0.z + v0.w + v1.x + v1.y + v1.z + v1.w;
    float s2 = v0.x * v0.x + v0.y * v0.y + v0.z * v0.z + v0.w * v0.w +
               v1.x * v1.x + v1.y * v1.y + v1.z * v1.z + v1.w * v1.w;
    s1 = wsum64(s1); s2 = wsum64(s2);
    __shared__ float r1[4], r2[4];
    if ((t & 63) == 0) { r1[t >> 6] = s1; r2[t >> 6] = s2; }
    __syncthreads();
    float S1 = r1[0] + r1[1] + r1[2] + r1[3];
    float S2 = r2[0] + r2[1] + r2[2] + r2[3];
    float mu = S1 * (1.f / 2048.f);
    float var = S2 * (1.f / 2048.f) - mu * mu;
    float rstd = rsqrtf(var + 1e-6f);
    float4 w0 = *(const float4*)(pw + c0), b0 = *(const float4*)(pb + c0);
    float4 w1 = *(const float4*)(pw + c1), b1 = *(const float4*)(pb + c1);
    ushort4 o0, o1;
    o0.x = f2bf((v0.x - mu) * rstd * w0.x + b0.x);
    o0.y = f2bf((v0.y - mu) * rstd * w0.y + b0.y);
    o0.z = f2bf((v0.z - mu) * rstd * w0.z + b0.z);
    o0.w = f2bf((v0.w - mu) * rstd * w0.w + b0.w);
    o1.x = f2bf((v1.x - mu) * rstd * w1.x + b1.x);
    o1.y = f2bf((v1.y - mu) * rstd * w1.y + b1.y);
    o1.z = f2bf((v1.z - mu) * rstd * w1.z + b1.z);
    o1.w = f2bf((v1.w - mu) * rstd * w1.w + b1.w);
    *(ushort4*)(Yb + (size_t)tok * Dd + c0) = o0;
    *(ushort4*)(Yb + (size_t)tok * Dd + c1) = o1;
}

extern "C" void kernel_launch(void* const* d_in, const int* in_sizes, int n_in,
                              void* d_out, int out_size, void* d_ws, size_t ws_size,
                              hipStream_t stream) {
    const float* hs   = (const float*)d_in[0];
    const float* wq_w = (const float*)d_in[1];
    const float* wq_b = (const float*)d_in[2];
    const float* wk_w = (const float*)d_in[3];
    const float* wk_b = (const float*)d_in[4];
    const float* wv_w = (const float*)d_in[5];
    const float* wv_b = (const float*)d_in[6];
    const float* wo_w = (const float*)d_in[7];
    const float* wo_b = (const float*)d_in[8];
    const float* lnw  = (const float*)d_in[9];
    const float* lnb  = (const float*)d_in[10];
    const float* lr_w = (const float*)d_in[11];
    const float* lr_b = (const float*)d_in[12];
    const float* W1   = (const float*)d_in[13];
    const float* b1   = (const float*)d_in[14];
    const float* pnw  = (const float*)d_in[15];
    const float* pnb  = (const float*)d_in[16];
    float* out = (float*)d_out;

    char* ws = (char*)d_ws;
    size_t off = 0;
    auto alloc = [&](size_t bytes) -> void* {
        void* p = ws + off; off += (bytes + 255) & ~(size_t)255; return p;
    };
    unsigned short* hsb = (unsigned short*)alloc((size_t)MTOK * Dd * 2);
    unsigned short* wtb = (unsigned short*)alloc((size_t)Dd * Dd * 2);
    float* XQ = (float*)alloc((size_t)MTOK * Dd * 4);
    float* XK = (float*)alloc((size_t)MTOK * Dd * 4);
    float* XV = (float*)alloc((size_t)MTOK * Dd * 4);
    float* lrbuf = (float*)alloc((size_t)Bb * Hh * Ls * 4);
    float* Y = XQ;                 // safe alias (per-chain row/col ownership; writes trail reads)
    unsigned short* Yb = hsb;      // hsb dead after QKV GEMMs

    dim3 blk(256);
    cast_hs_kernel<<<dim3(MTOK * Dd / 1024), blk, 0, stream>>>(hs, hsb);

    transpose_cast_kernel<<<dim3(1024), blk, 0, stream>>>(wq_w, wtb);
    gemm_bt_kernel<<<dim3(64, 16), blk, 0, stream>>>(hsb, wtb, wq_b, XQ, MTOK, Dd, Dd);
    transpose_cast_kernel<<<dim3(1024), blk, 0, stream>>>(wk_w, wtb);
    gemm_bt_kernel<<<dim3(64, 16), blk, 0, stream>>>(hsb, wtb, wk_b, XK, MTOK, Dd, Dd);
    transpose_cast_kernel<<<dim3(1024), blk, 0, stream>>>(wv_w, wtb);
    gemm_bt_kernel<<<dim3(64, 16), blk, 0, stream>>>(hsb, wtb, wv_b, XV, MTOK, Dd, Dd);

    lr_kernel<<<dim3(MTOK), blk, 0, stream>>>(hs, lr_w, lr_b, lrbuf);

    scan_kernel<<<dim3(Bb * Hh), blk, 0, stream>>>(XQ, XK, XV, lrbuf, W1, b1, lnw, lnb, Y);

    postnorm_kernel<<<dim3(MTOK), blk, 0, stream>>>(Y, pnw, pnb, Yb);

    transpose_cast_kernel<<<dim3(1024), blk, 0, stream>>>(wo_w, wtb);
    gemm_bt_kernel<<<dim3(64, 16), blk, 0, stream>>>(Yb, wtb, wo_b, out, MTOK, Dd, Dd);
}

// Round 6
// 1408.277 us; speedup vs baseline: 1.0279x; 1.0183x over previous
//
#include <hip/hip_runtime.h>
#include <hip/hip_bf16.h>
#include <cstdint>
#include <cstddef>

#define DEV __device__ __forceinline__

constexpr int Bb = 2, Ls = 4096, Dd = 2048, Hh = 32, HD = 64, MBK = 16, NMBc = 256;
constexpr int MTOK = Bb * Ls; // 8192 tokens

typedef __bf16 bf16x8 __attribute__((ext_vector_type(8)));
typedef float  f32x4  __attribute__((ext_vector_type(4)));

// hardware RNE f32->bf16
DEV unsigned short f2bf(float f) {
    union { __bf16 h; unsigned short u; } x;
    x.h = (__bf16)f;
    return x.u;
}
DEV float b2f(unsigned short u) {
    union { unsigned int i; float f; } x; x.i = ((unsigned int)u) << 16;
    return x.f;
}

// 64-lane sum via DPP; lane 63 holds total, readlane broadcasts (uniform use).
DEV float wsum64(float v) {
    int t;
    t = __builtin_amdgcn_update_dpp(0, __float_as_int(v), 0x111, 0xf, 0xf, true); v += __int_as_float(t);
    t = __builtin_amdgcn_update_dpp(0, __float_as_int(v), 0x112, 0xf, 0xf, true); v += __int_as_float(t);
    t = __builtin_amdgcn_update_dpp(0, __float_as_int(v), 0x114, 0xf, 0xf, true); v += __int_as_float(t);
    t = __builtin_amdgcn_update_dpp(0, __float_as_int(v), 0x118, 0xf, 0xf, true); v += __int_as_float(t);
    t = __builtin_amdgcn_update_dpp(0, __float_as_int(v), 0x142, 0xa, 0xf, true); v += __int_as_float(t);
    t = __builtin_amdgcn_update_dpp(0, __float_as_int(v), 0x143, 0xc, 0xf, true); v += __int_as_float(t);
    return __int_as_float(__builtin_amdgcn_readlane(__float_as_int(v), 63));
}

// 16-lane (DPP row) rotate-reduce sum: every lane of each row-of-16 gets the row total.
DEV float rsum16(float v) {
    int t;
    t = __builtin_amdgcn_update_dpp(0, __float_as_int(v), 0x121, 0xf, 0xf, true); v += __int_as_float(t); // ror1
    t = __builtin_amdgcn_update_dpp(0, __float_as_int(v), 0x122, 0xf, 0xf, true); v += __int_as_float(t); // ror2
    t = __builtin_amdgcn_update_dpp(0, __float_as_int(v), 0x124, 0xf, 0xf, true); v += __int_as_float(t); // ror4
    t = __builtin_amdgcn_update_dpp(0, __float_as_int(v), 0x128, 0xf, 0xf, true); v += __int_as_float(t); // ror8
    return v;
}

// runtime-n select from 4 scalars (no dynamic indexing -> no scratch)
DEV float sel4(int n, float a, float b, float c, float d) {
    float v = (n == 1) ? b : a;
    v = (n == 2) ? c : v;
    v = (n == 3) ? d : v;
    return v;
}

DEV void g2l16(const void* g, void* l) {
    __builtin_amdgcn_global_load_lds(
        (__attribute__((address_space(1))) void*)(g),
        (__attribute__((address_space(3))) void*)(l), 16, 0, 0);
}

// ---------------- cast hidden_states fp32 -> bf16 ----------------
__global__ __launch_bounds__(256) void cast_hs_kernel(const float* __restrict__ src,
                                                      unsigned short* __restrict__ dst) {
    int i = (blockIdx.x * 256 + threadIdx.x) * 4;
    float4 v = *(const float4*)(src + i);
    ushort4 o; o.x = f2bf(v.x); o.y = f2bf(v.y); o.z = f2bf(v.z); o.w = f2bf(v.w);
    *(ushort4*)(dst + i) = o;
}

// ---------------- transpose + cast weight: W[k][n] fp32 -> Wt[n][k] bf16 ----------------
__global__ __launch_bounds__(256) void transpose_cast_kernel(const float* __restrict__ W,
                                                             unsigned short* __restrict__ Wt) {
    __shared__ float tile[64][65];
    int bx = blockIdx.x & 31;   // k-tile
    int by = blockIdx.x >> 5;   // n-tile
    int t = threadIdx.x;
    int r = t >> 4, c4 = (t & 15) * 4;
    #pragma unroll
    for (int i = 0; i < 4; ++i) {
        int row = r + i * 16;
        float4 v = *(const float4*)(W + (size_t)(bx * 64 + row) * Dd + by * 64 + c4);
        tile[row][c4 + 0] = v.x; tile[row][c4 + 1] = v.y;
        tile[row][c4 + 2] = v.z; tile[row][c4 + 3] = v.w;
    }
    __syncthreads();
    #pragma unroll
    for (int i = 0; i < 4; ++i) {
        int row = r + i * 16; // n index
        ushort4 o;
        o.x = f2bf(tile[c4 + 0][row]); o.y = f2bf(tile[c4 + 1][row]);
        o.z = f2bf(tile[c4 + 2][row]); o.w = f2bf(tile[c4 + 3][row]);
        *(ushort4*)(Wt + (size_t)(by * 64 + row) * Dd + bx * 64 + c4) = o;
    }
}

// ---------------- bf16 MFMA GEMM:  C[M,N] = A[M,K] @ Bt[N,K]^T + bias ----------------
__global__ __launch_bounds__(256) void gemm_bt_kernel(const unsigned short* __restrict__ A,
                                                      const unsigned short* __restrict__ Bt,
                                                      const float* __restrict__ bias,
                                                      float* __restrict__ C,
                                                      int M, int N, int Kd) {
    __shared__ unsigned short sA[128 * 64];
    __shared__ unsigned short sB[128 * 64];
    int t = threadIdx.x;
    int lane = t & 63;
    int wid = t >> 6, wm = wid >> 1, wn = wid & 1;
    int quad = lane >> 4, c = lane & 15;
    int bm = blockIdx.x, bn = blockIdx.y;

    const unsigned short* pa[4]; const unsigned short* pb[4];
    unsigned short* la[4]; unsigned short* lb[4];
    #pragma unroll
    for (int i = 0; i < 4; ++i) {
        int lin = i * 256 + t;
        int row = lin >> 3, blk = lin & 7;
        int oct = blk ^ (row & 7);
        pa[i] = A  + (size_t)(bm * 128 + row) * Kd + oct * 8;
        pb[i] = Bt + (size_t)(bn * 128 + row) * Kd + oct * 8;
        la[i] = sA + lin * 8;
        lb[i] = sB + lin * 8;
    }

    f32x4 acc[4][4];
    #pragma unroll
    for (int i = 0; i < 4; ++i)
        #pragma unroll
        for (int j = 0; j < 4; ++j)
            #pragma unroll
            for (int r = 0; r < 4; ++r) acc[i][j][r] = 0.f;

    const char* sAc = (const char*)sA;
    const char* sBc = (const char*)sB;
    int rowA0 = wm * 64 + c, rowB0 = wn * 64 + c;
    int sw = (c & 7);

    int nkt = Kd >> 6;
    for (int kt = 0; kt < nkt; ++kt) {
        #pragma unroll
        for (int i = 0; i < 4; ++i) {
            g2l16(pa[i], la[i]);
            g2l16(pb[i], lb[i]);
            pa[i] += 64; pb[i] += 64;
        }
        __syncthreads();
        #pragma unroll
        for (int s = 0; s < 2; ++s) {
            bf16x8 af[4], bfv[4];
            int so = (s << 2) | quad;
            #pragma unroll
            for (int mt = 0; mt < 4; ++mt)
                af[mt] = *(const bf16x8*)(sAc + (rowA0 + mt * 16) * 128 + ((so ^ sw) * 16));
            #pragma unroll
            for (int nt = 0; nt < 4; ++nt)
                bfv[nt] = *(const bf16x8*)(sBc + (rowB0 + nt * 16) * 128 + ((so ^ sw) * 16));
            #pragma unroll
            for (int mt = 0; mt < 4; ++mt)
                #pragma unroll
                for (int nt = 0; nt < 4; ++nt)
                    acc[mt][nt] = __builtin_amdgcn_mfma_f32_16x16x32_bf16(af[mt], bfv[nt], acc[mt][nt], 0, 0, 0);
        }
        __syncthreads();
    }

    float bv[4];
    #pragma unroll
    for (int nt = 0; nt < 4; ++nt) bv[nt] = bias[bn * 128 + wn * 64 + nt * 16 + c];
    #pragma unroll
    for (int mt = 0; mt < 4; ++mt)
        #pragma unroll
        for (int r = 0; r < 4; ++r) {
            int row = bm * 128 + wm * 64 + mt * 16 + quad * 4 + r;
            float* cp = C + (size_t)row * N + bn * 128 + wn * 64 + c;
            #pragma unroll
            for (int nt = 0; nt < 4; ++nt) cp[nt * 16] = acc[mt][nt][r] + bv[nt];
        }
}

// ---------------- lr: s[b,h,l] = sigmoid(hs[b,l,:]·lr_w[h,:] + lr_b[h]) / (HD*K) ----------------
__global__ __launch_bounds__(256) void lr_kernel(const float* __restrict__ hs,
                                                 const float* __restrict__ lrw,
                                                 const float* __restrict__ lrb,
                                                 float* __restrict__ lr_out) {
    int tok = blockIdx.x; // b*L + l
    int t = threadIdx.x;
    int h = t >> 3, j0 = t & 7;
    const float* row = hs + (size_t)tok * Dd;
    const float* wr = lrw + (size_t)h * Dd;
    float p = 0.f;
    for (int j = j0 * 4; j < Dd; j += 32) {
        float4 a = *(const float4*)(row + j);
        float4 w = *(const float4*)(wr + j);
        p += a.x * w.x + a.y * w.y + a.z * w.z + a.w * w.w;
    }
    __shared__ float red[32][8];
    red[h][j0] = p;
    __syncthreads();
    if (t < 32) {
        float s = 0.f;
        #pragma unroll
        for (int i = 0; i < 8; ++i) s += red[t][i];
        s += lrb[t];
        s = 1.f / (1.f + expf(-s));
        s *= 1.0f / (HD * MBK);
        int b = tok >> 12, l = tok & (Ls - 1);
        lr_out[(size_t)(b * Hh + t) * Ls + l] = s;
    }
}

// staging helpers (role-split): 16 rows x 16 float4 per role group of 256 threads
DEV void stage_q_half(float4 q, float* tq, unsigned short* bq, int rowp, int c4p) {
    float rq = 1.f / fmaxf(sqrtf(rsum16(q.x*q.x + q.y*q.y + q.z*q.z + q.w*q.w)), 1e-12f);
    q.x *= rq; q.y *= rq; q.z *= rq; q.w *= rq;
    *(float4*)&tq[rowp * 68 + c4p] = q;
    ushort4 qb;
    qb.x = f2bf(q.x); qb.y = f2bf(q.y); qb.z = f2bf(q.z); qb.w = f2bf(q.w);
    *(ushort4*)&bq[rowp * 72 + c4p] = qb;
}
DEV void stage_kv_half(float4 k, float4 v, float* tk, float* tv, unsigned short* bk,
                       int rowp, int c4p, float4 lnw4, float4 lnb4) {
    float rk = 1.f / fmaxf(sqrtf(rsum16(k.x*k.x + k.y*k.y + k.z*k.z + k.w*k.w)), 1e-12f);
    k.x *= rk; k.y *= rk; k.z *= rk; k.w *= rk;
    float4 df; df.x = v.x - k.x; df.y = v.y - k.y; df.z = v.z - k.z; df.w = v.w - k.w;
    float mu = rsum16(df.x + df.y + df.z + df.w) * (1.f / 64.f);
    float4 cc; cc.x = df.x - mu; cc.y = df.y - mu; cc.z = df.z - mu; cc.w = df.w - mu;
    float var = rsum16(cc.x*cc.x + cc.y*cc.y + cc.z*cc.z + cc.w*cc.w) * (1.f / 63.f); // ddof=1
    float rs = 1.f / (sqrtf(var) + 1e-8f);
    float4 vn;
    vn.x = lnw4.x * cc.x * rs + lnb4.x + k.x;
    vn.y = lnw4.y * cc.y * rs + lnb4.y + k.y;
    vn.z = lnw4.z * cc.z * rs + lnb4.z + k.z;
    vn.w = lnw4.w * cc.w * rs + lnb4.w + k.w;
    *(float4*)&tk[rowp * 68 + c4p] = k;
    *(float4*)&tv[rowp * 68 + c4p] = vn;
    ushort4 kb;
    kb.x = f2bf(k.x); kb.y = f2bf(k.y); kb.z = f2bf(k.z); kb.w = f2bf(k.w);
    *(ushort4*)&bk[rowp * 72 + c4p] = kb;
}

// ---------------- MFMA TTT scan: 8 waves per (b,h) chain (role split) ----------------
// role0 = waves 0-3 (slab wz=w): Z1 MFMAs + zTr + z1-LN partials (A); W1 RMW (C).
// role1 = waves 4-7 (slab wz=w-4): Zbar MFMAs (A; wave4 adds attn); deferred
//   phase-D output of step n-1 (B); Zbar finish + LN partials + xq carry (C).
// Grad phase (B): 16 rows / 8 waves = 2 rows per wave.
// 3 barriers/step: B1 (zTr/s1p/attb ready), B2 (gbufT/sxkT/pb ready),
// B3 loop-end (W1 slab updated by role0 before role0+role1 read it in A(n+1)).
// Cross-step hazards audited: every LDS write/read pair crosses >=1 barrier.
__global__ __launch_bounds__(512, 1) void scan_kernel(const float* __restrict__ XQ,
                                                      const float* __restrict__ XK,
                                                      const float* __restrict__ XV,
                                                      const float* __restrict__ lrbuf,
                                                      const float* __restrict__ W1in,
                                                      const float* __restrict__ b1in,
                                                      const float* __restrict__ lnw_g,
                                                      const float* __restrict__ lnb_g,
                                                      float* __restrict__ Y) {
    int bh = blockIdx.x;          // b*H + h
    int b = bh >> 5, h = bh & 31;
    int t = threadIdx.x;
    int w = t >> 6;               // wave 0..7
    int lane = t & 63;
    int q = lane >> 4, n = lane & 15;
    int role = w >> 2, wz = w & 3;
    int gc = 16 * wz + n;         // this lane's C-layout global column (slab wz)

    __shared__ float tiles[2][3][16 * 68];     // [buf][xq,xk,xv][token][feat] fp32
    __shared__ unsigned short tbq[2][16 * 72]; // bf16 xq tiles
    __shared__ unsigned short tbk[2][16 * 72]; // bf16 xk tiles
    __shared__ float svb[2][16];
    __shared__ unsigned short wt_hi[64 * 72];  // [col][k]
    __shared__ unsigned short wt_lo[64 * 72];
    __shared__ float zTr[16 * 68];             // z1 row-major bounce [token][col]
    __shared__ unsigned short gbufT[64 * 32];  // [col][k] bf16, k>=16 zero
    __shared__ unsigned short sxkT[64 * 32];   // [col][k] bf16, k>=16 zero
    __shared__ unsigned short attb[2][16 * 32];// [buf][i][j] bf16, j>=16 zero
    __shared__ float pb[8 * 64];               // b1-partials [wave][col]
    __shared__ float s1p[16 * 4], s2p[16 * 4]; // z1 LN partials [row][slab-wave]
    __shared__ float s1z[16 * 4], s2z[16 * 4]; // zbar LN partials [row][slab-wave]

    // ---- init W1 as hi/lo bf16, transposed ----
    #pragma unroll
    for (int i = 0; i < 8; ++i) {
        int k = i * 8 + w;        // 0..63
        float val = W1in[(size_t)h * 4096 + (size_t)k * 64 + lane];
        unsigned short hi = f2bf(val);
        unsigned short lo = f2bf(val - b2f(hi));
        wt_hi[lane * 72 + k] = hi;
        wt_lo[lane * 72 + k] = lo;
    }
    // ---- zero pads ----
    #pragma unroll
    for (int i = 0; i < 4; ++i) { gbufT[i * 512 + t] = 0; sxkT[i * 512 + t] = 0; }
    #pragma unroll
    for (int i = 0; i < 2; ++i) ((unsigned short*)attb)[i * 512 + t] = 0;

    float b1r = b1in[h * 64 + lane];   // lane-indexed (grad phase)
    float b1c = b1in[h * 64 + gc];     // gc-indexed (A partials / zbar / D)
    float lnwr = lnw_g[h * 64 + lane];
    float lnbr = lnb_g[h * 64 + lane];
    float lnwc = lnw_g[h * 64 + gc];
    float lnbc = lnb_g[h * 64 + gc];

    const size_t gbase = ((size_t)b * Ls) * Dd + h * 64;
    const float* lrp = lrbuf + (size_t)bh * Ls;

    int ts = t & 255;
    int rowp = ts >> 4, c4p = (ts & 15) * 4;   // staging: 16 rows x 16 float4 per role
    float4 lnw4 = *(const float4*)(lnw_g + h * 64 + c4p);
    float4 lnb4 = *(const float4*)(lnb_g + h * 64 + c4p);

    // ---- prologue: step 0 staged (+fixup), prefetch step 1 (raw) ----
    float4 preq, prek, prev;
    if (role == 0) {
        float4 q0 = *(const float4*)(XQ + gbase + (size_t)rowp * Dd + c4p);
        stage_q_half(q0, &tiles[0][0][0], tbq[0], rowp, c4p);
        preq = *(const float4*)(XQ + gbase + (size_t)(16 + rowp) * Dd + c4p);
    } else {
        float4 k0 = *(const float4*)(XK + gbase + (size_t)rowp * Dd + c4p);
        float4 v0 = *(const float4*)(XV + gbase + (size_t)rowp * Dd + c4p);
        stage_kv_half(k0, v0, &tiles[0][1][0], &tiles[0][2][0], tbk[0], rowp, c4p, lnw4, lnb4);
        prek = *(const float4*)(XK + gbase + (size_t)(16 + rowp) * Dd + c4p);
        prev = *(const float4*)(XV + gbase + (size_t)(16 + rowp) * Dd + c4p);
    }
    if (t < 16) svb[0][t] = lrp[t];
    float presv = (t < 16) ? lrp[16 + t] : 0.f;
    __syncthreads();

    const f32x4 zero4 = {0.f, 0.f, 0.f, 0.f};
    float zbar_p[4] = {0.f, 0.f, 0.f, 0.f};   // role1 deferred-D carries
    float xqc_p[4]  = {0.f, 0.f, 0.f, 0.f};

    for (int nmb = 0; nmb < NMBc; ++nmb) {
        int cb = nmb & 1, nb2 = cb ^ 1;
        int l0 = nmb * 16;
        // ---- top: stage step n+1 from prefetch regs; issue prefetch n+2 ----
        int lp = (l0 + 32 <= Ls - 16) ? (l0 + 32) : (Ls - 16);
        if (role == 0) {
            stage_q_half(preq, &tiles[nb2][0][0], tbq[nb2], rowp, c4p);
            preq = *(const float4*)(XQ + gbase + (size_t)(lp + rowp) * Dd + c4p);
        } else {
            stage_kv_half(prek, prev, &tiles[nb2][1][0], &tiles[nb2][2][0], tbk[nb2],
                          rowp, c4p, lnw4, lnb4);
            prek = *(const float4*)(XK + gbase + (size_t)(lp + rowp) * Dd + c4p);
            prev = *(const float4*)(XV + gbase + (size_t)(lp + rowp) * Dd + c4p);
        }
        if (t < 16) svb[nb2][t] = presv;
        presv = (t < 16) ? lrp[lp + t] : 0.f;

        const float* xqs = &tiles[cb][0][0];
        const float* xks = &tiles[cb][1][0];
        const float* xvs = &tiles[cb][2][0];
        const unsigned short* bqs = tbq[cb];
        const unsigned short* bks = tbk[cb];

        // ---- W1 B-frags (slab wz; read by BOTH roles; updated by role0 in C, ordered by B3) ----
        bf16x8 wh0 = *(const bf16x8*)&wt_hi[gc * 72 + 8 * q];
        bf16x8 wh1 = *(const bf16x8*)&wt_hi[gc * 72 + 32 + 8 * q];
        bf16x8 wl0 = *(const bf16x8*)&wt_lo[gc * 72 + 8 * q];
        bf16x8 wl1 = *(const bf16x8*)&wt_lo[gc * 72 + 32 + 8 * q];

        f32x4 zb = zero4;   // role1 carries zb through B1/B2
        if (role == 0) {
            // ---- Z1 slab (hi/lo split, depth 2) ----
            bf16x8 kf0 = *(const bf16x8*)&bks[n * 72 + 8 * q];
            bf16x8 kf1 = *(const bf16x8*)&bks[n * 72 + 32 + 8 * q];
            f32x4 z1 = __builtin_amdgcn_mfma_f32_16x16x32_bf16(kf0, wh0, zero4, 0, 0, 0);
            z1 = __builtin_amdgcn_mfma_f32_16x16x32_bf16(kf1, wh1, z1, 0, 0, 0);
            f32x4 z1l = __builtin_amdgcn_mfma_f32_16x16x32_bf16(kf0, wl0, zero4, 0, 0, 0);
            z1l = __builtin_amdgcn_mfma_f32_16x16x32_bf16(kf1, wl1, z1l, 0, 0, 0);
            z1 = z1 + z1l;
            // bounce row-major + z1-LN partials (zar = z1 + b1c)
            float p1[4], p2[4];
            #pragma unroll
            for (int r = 0; r < 4; ++r) {
                zTr[(4 * q + r) * 68 + gc] = z1[r];
                float za = z1[r] + b1c;
                p1[r] = rsum16(za);
                p2[r] = rsum16(za * za);
            }
            if (n < 4) {
                s1p[(4 * q + n) * 4 + wz] = sel4(n, p1[0], p1[1], p1[2], p1[3]);
                s2p[(4 * q + n) * 4 + wz] = sel4(n, p2[0], p2[1], p2[2], p2[3]);
            }
        } else {
            // ---- Zbar partial (hi/lo split, depth 2); wave 4 adds attn ----
            bf16x8 qf0 = *(const bf16x8*)&bqs[n * 72 + 8 * q];
            bf16x8 qf1 = *(const bf16x8*)&bqs[n * 72 + 32 + 8 * q];
            zb = __builtin_amdgcn_mfma_f32_16x16x32_bf16(qf0, wh0, zero4, 0, 0, 0);
            zb = __builtin_amdgcn_mfma_f32_16x16x32_bf16(qf1, wh1, zb, 0, 0, 0);
            f32x4 zbl = __builtin_amdgcn_mfma_f32_16x16x32_bf16(qf0, wl0, zero4, 0, 0, 0);
            zbl = __builtin_amdgcn_mfma_f32_16x16x32_bf16(qf1, wl1, zbl, 0, 0, 0);
            zb = zb + zbl;
            if (w == 4) {
                bf16x8 kf0 = *(const bf16x8*)&bks[n * 72 + 8 * q];
                bf16x8 kf1 = *(const bf16x8*)&bks[n * 72 + 32 + 8 * q];
                f32x4 aacc = __builtin_amdgcn_mfma_f32_16x16x32_bf16(qf1, kf1, zero4, 0, 0, 0);
                aacc = __builtin_amdgcn_mfma_f32_16x16x32_bf16(qf0, kf0, aacc, 0, 0, 0);
                float svn = svb[cb][n];
                #pragma unroll
                for (int r = 0; r < 4; ++r) {
                    int i = 4 * q + r;
                    attb[cb][i * 32 + n] = f2bf((i >= n) ? (-svn * (aacc[r] + 1.f)) : 0.f);
                }
            }
        }
        __syncthreads(); // B1

        // ======== deferred phase D (step n-1) by role1: zbar LN + Y store ========
        if (role == 1 && nmb > 0) {
            int l0p = l0 - 16;
            #pragma unroll
            for (int r = 0; r < 4; ++r) {
                int row = 4 * q + r;
                float4 a1 = *(const float4*)&s1z[row * 4];
                float4 a2 = *(const float4*)&s2z[row * 4];
                float s1 = a1.x + a1.y + a1.z + a1.w;
                float s2 = a2.x + a2.y + a2.z + a2.w;
                float mu = s1 * (1.f / 64.f);
                float var = s2 * (1.f / 64.f) - mu * mu;
                float rstd = rsqrtf(var + 1e-6f);
                float o = lnwc * ((zbar_p[r] - mu) * rstd) + lnbc + xqc_p[r];
                Y[gbase + (size_t)(l0p + row) * Dd + gc] = o;
            }
        }

        // ======== grad phase: 2 rows per wave (rows 2w, 2w+1), lane = col ========
        float zar[2], xk_rm[2], xv_rm[2];
        #pragma unroll
        for (int r = 0; r < 2; ++r) {
            int rw = 2 * w + r;
            zar[r] = zTr[rw * 68 + lane] + b1r;
            xk_rm[r] = xks[rw * 68 + lane];
            xv_rm[r] = xvs[rw * 68 + lane];
        }
        float svr[2] = { svb[cb][2 * w], svb[cb][2 * w + 1] };
        float gr[2]; float pbv = 0.f;
        #pragma unroll
        for (int r = 0; r < 2; ++r) {
            int rw = 2 * w + r;
            float4 a1 = *(const float4*)&s1p[rw * 4];
            float4 a2 = *(const float4*)&s2p[rw * 4];
            float s1 = a1.x + a1.y + a1.z + a1.w;
            float s2 = a2.x + a2.y + a2.z + a2.w;
            float mu = s1 * (1.f / 64.f);
            float var = s2 * (1.f / 64.f) - mu * mu;
            float rstd = rsqrtf(var + 1e-6f);
            float xh = (zar[r] - mu) * rstd;
            float g = (lnwr * xh + lnbr - (xv_rm[r] - xk_rm[r])) * lnwr;
            float sg = wsum64(g);
            float sxg = wsum64(xh * g);
            gr[r] = (64.f * g - sg - xh * sxg) * rstd * (1.f / 64.f);
            pbv += svr[r] * gr[r];
        }
        {
            ushort2 gp, sp;
            gp.x = f2bf(gr[0]); gp.y = f2bf(gr[1]);
            sp.x = f2bf(svr[0] * xk_rm[0]); sp.y = f2bf(svr[1] * xk_rm[1]);
            *(ushort2*)&gbufT[lane * 32 + 2 * w] = gp;
            *(ushort2*)&sxkT[lane * 32 + 2 * w] = sp;
            pb[w * 64 + lane] = pbv;
        }
        __syncthreads(); // B2

        // ======== C-region ========
        bf16x8 gF = *(const bf16x8*)&gbufT[gc * 32 + 8 * q];
        if (role == 0) {
            // ---- W1 update: slab wz -= (sv.xk)^T @ grad ----
            #pragma unroll
            for (int tm = 0; tm < 4; ++tm) {
                bf16x8 ax = *(const bf16x8*)&sxkT[(16 * tm + n) * 32 + 8 * q];
                f32x4 dl = __builtin_amdgcn_mfma_f32_16x16x32_bf16(ax, gF, zero4, 0, 0, 0);
                int ko = 16 * tm + 4 * q;
                ushort4 h4 = *(ushort4*)&wt_hi[gc * 72 + ko];
                ushort4 l4 = *(ushort4*)&wt_lo[gc * 72 + ko];
                float w0 = b2f(h4.x) + b2f(l4.x) - dl[0];
                float w1 = b2f(h4.y) + b2f(l4.y) - dl[1];
                float w2 = b2f(h4.z) + b2f(l4.z) - dl[2];
                float w3 = b2f(h4.w) + b2f(l4.w) - dl[3];
                h4.x = f2bf(w0); l4.x = f2bf(w0 - b2f(h4.x));
                h4.y = f2bf(w1); l4.y = f2bf(w1 - b2f(h4.y));
                h4.z = f2bf(w2); l4.z = f2bf(w2 - b2f(h4.z));
                h4.w = f2bf(w3); l4.w = f2bf(w3 - b2f(h4.w));
                *(ushort4*)&wt_hi[gc * 72 + ko] = h4;
                *(ushort4*)&wt_lo[gc * 72 + ko] = l4;
            }
        } else {
            // ---- Zbar finish + LN partials + xq carry (uses OLD b1c) ----
            bf16x8 amF = *(const bf16x8*)&attb[cb][n * 32 + 8 * q];
            zb = __builtin_amdgcn_mfma_f32_16x16x32_bf16(amF, gF, zb, 0, 0, 0);
            float pz1[4], pz2[4];
            #pragma unroll
            for (int r = 0; r < 4; ++r) {
                zbar_p[r] = zb[r] + b1c;
                pz1[r] = rsum16(zbar_p[r]);
                pz2[r] = rsum16(zbar_p[r] * zbar_p[r]);
                xqc_p[r] = xqs[(4 * q + r) * 68 + gc];   // safe: tile[cb] overwritten at top(n+2)
            }
            if (n < 4) {
                s1z[(4 * q + n) * 4 + wz] = sel4(n, pz1[0], pz1[1], pz1[2], pz1[3]);
                s2z[(4 * q + n) * 4 + wz] = sel4(n, pz2[0], pz2[1], pz2[2], pz2[3]);
            }
        }
        // ---- b1 updates (old values used above) ----
        {
            float sbr = 0.f, sbc = 0.f;
            #pragma unroll
            for (int i = 0; i < 8; ++i) { sbr += pb[i * 64 + lane]; sbc += pb[i * 64 + gc]; }
            b1r -= sbr; b1c -= sbc;
        }
        __syncthreads(); // B3 (W1 slab + s1z/s2z ready for next step's readers)
    }

    // ---- epilogue: flush deferred phase D for step NMBc-1 (role1) ----
    if (role == 1) {
        int l0p = (NMBc - 1) * 16;
        #pragma unroll
        for (int r = 0; r < 4; ++r) {
            int row = 4 * q + r;
            float4 a1 = *(const float4*)&s1z[row * 4];
            float4 a2 = *(const float4*)&s2z[row * 4];
            float s1 = a1.x + a1.y + a1.z + a1.w;
            float s2 = a2.x + a2.y + a2.z + a2.w;
            float mu = s1 * (1.f / 64.f);
            float var = s2 * (1.f / 64.f) - mu * mu;
            float rstd = rsqrtf(var + 1e-6f);
            float o = lnwc * ((zbar_p[r] - mu) * rstd) + lnbc + xqc_p[r];
            Y[gbase + (size_t)(l0p + row) * Dd + gc] = o;
        }
    }
}

// ---------------- post layernorm over D + cast to bf16 ----------------
__global__ __launch_bounds__(256) void postnorm_kernel(const float* __restrict__ Y,
                                                       const float* __restrict__ pw,
                                                       const float* __restrict__ pb,
                                                       unsigned short* __restrict__ Yb) {
    int tok = blockIdx.x, t = threadIdx.x;
    const float* row = Y + (size_t)tok * Dd;
    int c0 = t * 4, c1 = 1024 + t * 4;
    float4 v0 = *(const float4*)(row + c0);
    float4 v1 = *(const float4*)(row + c1);
    float s1 = v0.x + v0.y + v0.z + v0.w + v1.x + v1.y + v1.z + v1.w;
    float s2 = v0.x * v0.x + v0.y * v0.y + v0.z * v0.z + v0.w * v0.w +
               v1.x * v1.x + v1.y * v1.y + v1.z * v1.z + v1.w * v1.w;
    s1 = wsum64(s1); s2 = wsum64(s2);
    __shared__ float r1[4], r2[4];
    if ((t & 63) == 0) { r1[t >> 6] = s1; r2[t >> 6] = s2; }
    __syncthreads();
    float S1 = r1[0] + r1[1] + r1[2] + r1[3];
    float S2 = r2[0] + r2[1] + r2[2] + r2[3];
    float mu = S1 * (1.f / 2048.f);
    float var = S2 * (1.f / 2048.f) - mu * mu;
    float rstd = rsqrtf(var + 1e-6f);
    float4 w0 = *(const float4*)(pw + c0), b0 = *(const float4*)(pb + c0);
    float4 w1 = *(const float4*)(pw + c1), b1 = *(const float4*)(pb + c1);
    ushort4 o0, o1;
    o0.x = f2bf((v0.x - mu) * rstd * w0.x + b0.x);
    o0.y = f2bf((v0.y - mu) * rstd * w0.y + b0.y);
    o0.z = f2bf((v0.z - mu) * rstd * w0.z + b0.z);
    o0.w = f2bf((v0.w - mu) * rstd * w0.w + b0.w);
    o1.x = f2bf((v1.x - mu) * rstd * w1.x + b1.x);
    o1.y = f2bf((v1.y - mu) * rstd * w1.y + b1.y);
    o1.z = f2bf((v1.z - mu) * rstd * w1.z + b1.z);
    o1.w = f2bf((v1.w - mu) * rstd * w1.w + b1.w);
    *(ushort4*)(Yb + (size_t)tok * Dd + c0) = o0;
    *(ushort4*)(Yb + (size_t)tok * Dd + c1) = o1;
}

extern "C" void kernel_launch(void* const* d_in, const int* in_sizes, int n_in,
                              void* d_out, int out_size, void* d_ws, size_t ws_size,
                              hipStream_t stream) {
    const float* hs   = (const float*)d_in[0];
    const float* wq_w = (const float*)d_in[1];
    const float* wq_b = (const float*)d_in[2];
    const float* wk_w = (const float*)d_in[3];
    const float* wk_b = (const float*)d_in[4];
    const float* wv_w = (const float*)d_in[5];
    const float* wv_b = (const float*)d_in[6];
    const float* wo_w = (const float*)d_in[7];
    const float* wo_b = (const float*)d_in[8];
    const float* lnw  = (const float*)d_in[9];
    const float* lnb  = (const float*)d_in[10];
    const float* lr_w = (const float*)d_in[11];
    const float* lr_b = (const float*)d_in[12];
    const float* W1   = (const float*)d_in[13];
    const float* b1   = (const float*)d_in[14];
    const float* pnw  = (const float*)d_in[15];
    const float* pnb  = (const float*)d_in[16];
    float* out = (float*)d_out;

    char* ws = (char*)d_ws;
    size_t off = 0;
    auto alloc = [&](size_t bytes) -> void* {
        void* p = ws + off; off += (bytes + 255) & ~(size_t)255; return p;
    };
    unsigned short* hsb = (unsigned short*)alloc((size_t)MTOK * Dd * 2);
    unsigned short* wtb = (unsigned short*)alloc((size_t)Dd * Dd * 2);
    float* XQ = (float*)alloc((size_t)MTOK * Dd * 4);
    float* XK = (float*)alloc((size_t)MTOK * Dd * 4);
    float* XV = (float*)alloc((size_t)MTOK * Dd * 4);
    float* lrbuf = (float*)alloc((size_t)Bb * Hh * Ls * 4);
    float* Y = XQ;                 // safe alias (per-chain row/col ownership; writes trail reads)
    unsigned short* Yb = hsb;      // hsb dead after QKV GEMMs

    dim3 blk(256);
    cast_hs_kernel<<<dim3(MTOK * Dd / 1024), blk, 0, stream>>>(hs, hsb);

    transpose_cast_kernel<<<dim3(1024), blk, 0, stream>>>(wq_w, wtb);
    gemm_bt_kernel<<<dim3(64, 16), blk, 0, stream>>>(hsb, wtb, wq_b, XQ, MTOK, Dd, Dd);
    transpose_cast_kernel<<<dim3(1024), blk, 0, stream>>>(wk_w, wtb);
    gemm_bt_kernel<<<dim3(64, 16), blk, 0, stream>>>(hsb, wtb, wk_b, XK, MTOK, Dd, Dd);
    transpose_cast_kernel<<<dim3(1024), blk, 0, stream>>>(wv_w, wtb);
    gemm_bt_kernel<<<dim3(64, 16), blk, 0, stream>>>(hsb, wtb, wv_b, XV, MTOK, Dd, Dd);

    lr_kernel<<<dim3(MTOK), blk, 0, stream>>>(hs, lr_w, lr_b, lrbuf);

    scan_kernel<<<dim3(Bb * Hh), dim3(512), 0, stream>>>(XQ, XK, XV, lrbuf, W1, b1, lnw, lnb, Y);

    postnorm_kernel<<<dim3(MTOK), blk, 0, stream>>>(Y, pnw, pnb, Yb);

    transpose_cast_kernel<<<dim3(1024), blk, 0, stream>>>(wo_w, wtb);
    gemm_bt_kernel<<<dim3(64, 16), blk, 0, stream>>>(Yb, wtb, wo_b, out, MTOK, Dd, Dd);
}

// Round 7
// 1401.440 us; speedup vs baseline: 1.0329x; 1.0049x over previous
//
#include <hip/hip_runtime.h>
#include <hip/hip_bf16.h>
#include <cstdint>
#include <cstddef>

#define DEV __device__ __forceinline__

constexpr int Bb = 2, Ls = 4096, Dd = 2048, Hh = 32, HD = 64, MBK = 16, NMBc = 256;
constexpr int MTOK = Bb * Ls; // 8192 tokens

typedef __bf16 bf16x8 __attribute__((ext_vector_type(8)));
typedef float  f32x4  __attribute__((ext_vector_type(4)));

// hardware RNE f32->bf16
DEV unsigned short f2bf(float f) {
    union { __bf16 h; unsigned short u; } x;
    x.h = (__bf16)f;
    return x.u;
}
DEV float b2f(unsigned short u) {
    union { unsigned int i; float f; } x; x.i = ((unsigned int)u) << 16;
    return x.f;
}

// LDS-only barrier (T4): drain ONLY lgkmcnt (own LDS writes visible), raw s_barrier,
// leave vmcnt in flight -> prefetch global loads / Y stores cross barriers.
// __syncthreads would force s_waitcnt vmcnt(0) = full HBM latency exposed per step.
// Trailing memory-clobber asm pins post-barrier LDS reads below the barrier.
DEV void bsync() {
    asm volatile("s_waitcnt lgkmcnt(0)" ::: "memory");
    __builtin_amdgcn_s_barrier();
    asm volatile("" ::: "memory");
}

// 64-lane sum via DPP; lane 63 holds total, readlane broadcasts (uniform use).
DEV float wsum64(float v) {
    int t;
    t = __builtin_amdgcn_update_dpp(0, __float_as_int(v), 0x111, 0xf, 0xf, true); v += __int_as_float(t);
    t = __builtin_amdgcn_update_dpp(0, __float_as_int(v), 0x112, 0xf, 0xf, true); v += __int_as_float(t);
    t = __builtin_amdgcn_update_dpp(0, __float_as_int(v), 0x114, 0xf, 0xf, true); v += __int_as_float(t);
    t = __builtin_amdgcn_update_dpp(0, __float_as_int(v), 0x118, 0xf, 0xf, true); v += __int_as_float(t);
    t = __builtin_amdgcn_update_dpp(0, __float_as_int(v), 0x142, 0xa, 0xf, true); v += __int_as_float(t);
    t = __builtin_amdgcn_update_dpp(0, __float_as_int(v), 0x143, 0xc, 0xf, true); v += __int_as_float(t);
    return __int_as_float(__builtin_amdgcn_readlane(__float_as_int(v), 63));
}

// 16-lane (DPP row) rotate-reduce sum: every lane of each row-of-16 gets the row total.
DEV float rsum16(float v) {
    int t;
    t = __builtin_amdgcn_update_dpp(0, __float_as_int(v), 0x121, 0xf, 0xf, true); v += __int_as_float(t); // ror1
    t = __builtin_amdgcn_update_dpp(0, __float_as_int(v), 0x122, 0xf, 0xf, true); v += __int_as_float(t); // ror2
    t = __builtin_amdgcn_update_dpp(0, __float_as_int(v), 0x124, 0xf, 0xf, true); v += __int_as_float(t); // ror4
    t = __builtin_amdgcn_update_dpp(0, __float_as_int(v), 0x128, 0xf, 0xf, true); v += __int_as_float(t); // ror8
    return v;
}

// runtime-n select from 4 scalars (no dynamic indexing -> no scratch)
DEV float sel4(int n, float a, float b, float c, float d) {
    float v = (n == 1) ? b : a;
    v = (n == 2) ? c : v;
    v = (n == 3) ? d : v;
    return v;
}

DEV void g2l16(const void* g, void* l) {
    __builtin_amdgcn_global_load_lds(
        (__attribute__((address_space(1))) void*)(g),
        (__attribute__((address_space(3))) void*)(l), 16, 0, 0);
}

// ---------------- cast hidden_states fp32 -> bf16 ----------------
__global__ __launch_bounds__(256) void cast_hs_kernel(const float* __restrict__ src,
                                                      unsigned short* __restrict__ dst) {
    int i = (blockIdx.x * 256 + threadIdx.x) * 4;
    float4 v = *(const float4*)(src + i);
    ushort4 o; o.x = f2bf(v.x); o.y = f2bf(v.y); o.z = f2bf(v.z); o.w = f2bf(v.w);
    *(ushort4*)(dst + i) = o;
}

// ---------------- transpose + cast weight: W[k][n] fp32 -> Wt[n][k] bf16 ----------------
__global__ __launch_bounds__(256) void transpose_cast_kernel(const float* __restrict__ W,
                                                             unsigned short* __restrict__ Wt) {
    __shared__ float tile[64][65];
    int bx = blockIdx.x & 31;   // k-tile
    int by = blockIdx.x >> 5;   // n-tile
    int t = threadIdx.x;
    int r = t >> 4, c4 = (t & 15) * 4;
    #pragma unroll
    for (int i = 0; i < 4; ++i) {
        int row = r + i * 16;
        float4 v = *(const float4*)(W + (size_t)(bx * 64 + row) * Dd + by * 64 + c4);
        tile[row][c4 + 0] = v.x; tile[row][c4 + 1] = v.y;
        tile[row][c4 + 2] = v.z; tile[row][c4 + 3] = v.w;
    }
    __syncthreads();
    #pragma unroll
    for (int i = 0; i < 4; ++i) {
        int row = r + i * 16; // n index
        ushort4 o;
        o.x = f2bf(tile[c4 + 0][row]); o.y = f2bf(tile[c4 + 1][row]);
        o.z = f2bf(tile[c4 + 2][row]); o.w = f2bf(tile[c4 + 3][row]);
        *(ushort4*)(Wt + (size_t)(by * 64 + row) * Dd + bx * 64 + c4) = o;
    }
}

// ---------------- bf16 MFMA GEMM:  C[M,N] = A[M,K] @ Bt[N,K]^T + bias ----------------
__global__ __launch_bounds__(256) void gemm_bt_kernel(const unsigned short* __restrict__ A,
                                                      const unsigned short* __restrict__ Bt,
                                                      const float* __restrict__ bias,
                                                      float* __restrict__ C,
                                                      int M, int N, int Kd) {
    __shared__ unsigned short sA[128 * 64];
    __shared__ unsigned short sB[128 * 64];
    int t = threadIdx.x;
    int lane = t & 63;
    int wid = t >> 6, wm = wid >> 1, wn = wid & 1;
    int quad = lane >> 4, c = lane & 15;
    int bm = blockIdx.x, bn = blockIdx.y;

    const unsigned short* pa[4]; const unsigned short* pb[4];
    unsigned short* la[4]; unsigned short* lb[4];
    #pragma unroll
    for (int i = 0; i < 4; ++i) {
        int lin = i * 256 + t;
        int row = lin >> 3, blk = lin & 7;
        int oct = blk ^ (row & 7);
        pa[i] = A  + (size_t)(bm * 128 + row) * Kd + oct * 8;
        pb[i] = Bt + (size_t)(bn * 128 + row) * Kd + oct * 8;
        la[i] = sA + lin * 8;
        lb[i] = sB + lin * 8;
    }

    f32x4 acc[4][4];
    #pragma unroll
    for (int i = 0; i < 4; ++i)
        #pragma unroll
        for (int j = 0; j < 4; ++j)
            #pragma unroll
            for (int r = 0; r < 4; ++r) acc[i][j][r] = 0.f;

    const char* sAc = (const char*)sA;
    const char* sBc = (const char*)sB;
    int rowA0 = wm * 64 + c, rowB0 = wn * 64 + c;
    int sw = (c & 7);

    int nkt = Kd >> 6;
    for (int kt = 0; kt < nkt; ++kt) {
        #pragma unroll
        for (int i = 0; i < 4; ++i) {
            g2l16(pa[i], la[i]);
            g2l16(pb[i], lb[i]);
            pa[i] += 64; pb[i] += 64;
        }
        __syncthreads();
        #pragma unroll
        for (int s = 0; s < 2; ++s) {
            bf16x8 af[4], bfv[4];
            int so = (s << 2) | quad;
            #pragma unroll
            for (int mt = 0; mt < 4; ++mt)
                af[mt] = *(const bf16x8*)(sAc + (rowA0 + mt * 16) * 128 + ((so ^ sw) * 16));
            #pragma unroll
            for (int nt = 0; nt < 4; ++nt)
                bfv[nt] = *(const bf16x8*)(sBc + (rowB0 + nt * 16) * 128 + ((so ^ sw) * 16));
            #pragma unroll
            for (int mt = 0; mt < 4; ++mt)
                #pragma unroll
                for (int nt = 0; nt < 4; ++nt)
                    acc[mt][nt] = __builtin_amdgcn_mfma_f32_16x16x32_bf16(af[mt], bfv[nt], acc[mt][nt], 0, 0, 0);
        }
        __syncthreads();
    }

    float bv[4];
    #pragma unroll
    for (int nt = 0; nt < 4; ++nt) bv[nt] = bias[bn * 128 + wn * 64 + nt * 16 + c];
    #pragma unroll
    for (int mt = 0; mt < 4; ++mt)
        #pragma unroll
        for (int r = 0; r < 4; ++r) {
            int row = bm * 128 + wm * 64 + mt * 16 + quad * 4 + r;
            float* cp = C + (size_t)row * N + bn * 128 + wn * 64 + c;
            #pragma unroll
            for (int nt = 0; nt < 4; ++nt) cp[nt * 16] = acc[mt][nt][r] + bv[nt];
        }
}

// ---------------- lr: s[b,h,l] = sigmoid(hs[b,l,:]·lr_w[h,:] + lr_b[h]) / (HD*K) ----------------
__global__ __launch_bounds__(256) void lr_kernel(const float* __restrict__ hs,
                                                 const float* __restrict__ lrw,
                                                 const float* __restrict__ lrb,
                                                 float* __restrict__ lr_out) {
    int tok = blockIdx.x; // b*L + l
    int t = threadIdx.x;
    int h = t >> 3, j0 = t & 7;
    const float* row = hs + (size_t)tok * Dd;
    const float* wr = lrw + (size_t)h * Dd;
    float p = 0.f;
    for (int j = j0 * 4; j < Dd; j += 32) {
        float4 a = *(const float4*)(row + j);
        float4 w = *(const float4*)(wr + j);
        p += a.x * w.x + a.y * w.y + a.z * w.z + a.w * w.w;
    }
    __shared__ float red[32][8];
    red[h][j0] = p;
    __syncthreads();
    if (t < 32) {
        float s = 0.f;
        #pragma unroll
        for (int i = 0; i < 8; ++i) s += red[t][i];
        s += lrb[t];
        s = 1.f / (1.f + expf(-s));
        s *= 1.0f / (HD * MBK);
        int b = tok >> 12, l = tok & (Ls - 1);
        lr_out[(size_t)(b * Hh + t) * Ls + l] = s;
    }
}

// staging helpers (role-split): 16 rows x 16 float4 per role group of 256 threads
DEV void stage_q_half(float4 q, float* tq, unsigned short* bq, int rowp, int c4p) {
    float rq = 1.f / fmaxf(sqrtf(rsum16(q.x*q.x + q.y*q.y + q.z*q.z + q.w*q.w)), 1e-12f);
    q.x *= rq; q.y *= rq; q.z *= rq; q.w *= rq;
    *(float4*)&tq[rowp * 68 + c4p] = q;
    ushort4 qb;
    qb.x = f2bf(q.x); qb.y = f2bf(q.y); qb.z = f2bf(q.z); qb.w = f2bf(q.w);
    *(ushort4*)&bq[rowp * 72 + c4p] = qb;
}
DEV void stage_kv_half(float4 k, float4 v, float* tk, float* tv, unsigned short* bk,
                       int rowp, int c4p, float4 lnw4, float4 lnb4) {
    float rk = 1.f / fmaxf(sqrtf(rsum16(k.x*k.x + k.y*k.y + k.z*k.z + k.w*k.w)), 1e-12f);
    k.x *= rk; k.y *= rk; k.z *= rk; k.w *= rk;
    float4 df; df.x = v.x - k.x; df.y = v.y - k.y; df.z = v.z - k.z; df.w = v.w - k.w;
    float mu = rsum16(df.x + df.y + df.z + df.w) * (1.f / 64.f);
    float4 cc; cc.x = df.x - mu; cc.y = df.y - mu; cc.z = df.z - mu; cc.w = df.w - mu;
    float var = rsum16(cc.x*cc.x + cc.y*cc.y + cc.z*cc.z + cc.w*cc.w) * (1.f / 63.f); // ddof=1
    float rs = 1.f / (sqrtf(var) + 1e-8f);
    float4 vn;
    vn.x = lnw4.x * cc.x * rs + lnb4.x + k.x;
    vn.y = lnw4.y * cc.y * rs + lnb4.y + k.y;
    vn.z = lnw4.z * cc.z * rs + lnb4.z + k.z;
    vn.w = lnw4.w * cc.w * rs + lnb4.w + k.w;
    *(float4*)&tk[rowp * 68 + c4p] = k;
    *(float4*)&tv[rowp * 68 + c4p] = vn;
    ushort4 kb;
    kb.x = f2bf(k.x); kb.y = f2bf(k.y); kb.z = f2bf(k.z); kb.w = f2bf(k.w);
    *(ushort4*)&bk[rowp * 72 + c4p] = kb;
}

// ---------------- MFMA TTT scan: 8 waves per (b,h) chain (role split) ----------------
// role0 = waves 0-3 (slab wz=w): Z1 MFMAs + zTr + z1-LN partials (A); W1 RMW (C).
// role1 = waves 4-7 (slab wz=w-4): Zbar MFMAs (A; wave4 adds attn); deferred
//   phase-D output of step n-1 (B); Zbar finish + LN partials + xq carry (C).
// Grad phase (B): 16 rows / 8 waves = 2 rows per wave.
// 3 barriers/step via bsync() (lgkmcnt-only drain + raw s_barrier): global
// prefetch loads and Y stores stay in flight across barriers (T4); __syncthreads
// would expose a full HBM latency per step at B1.
__global__ __launch_bounds__(512, 1) void scan_kernel(const float* __restrict__ XQ,
                                                      const float* __restrict__ XK,
                                                      const float* __restrict__ XV,
                                                      const float* __restrict__ lrbuf,
                                                      const float* __restrict__ W1in,
                                                      const float* __restrict__ b1in,
                                                      const float* __restrict__ lnw_g,
                                                      const float* __restrict__ lnb_g,
                                                      float* __restrict__ Y) {
    int bh = blockIdx.x;          // b*H + h
    int b = bh >> 5, h = bh & 31;
    int t = threadIdx.x;
    int w = t >> 6;               // wave 0..7
    int lane = t & 63;
    int q = lane >> 4, n = lane & 15;
    int role = w >> 2, wz = w & 3;
    int gc = 16 * wz + n;         // this lane's C-layout global column (slab wz)

    __shared__ float tiles[2][3][16 * 68];     // [buf][xq,xk,xv][token][feat] fp32
    __shared__ unsigned short tbq[2][16 * 72]; // bf16 xq tiles
    __shared__ unsigned short tbk[2][16 * 72]; // bf16 xk tiles
    __shared__ float svb[2][16];
    __shared__ unsigned short wt_hi[64 * 72];  // [col][k]
    __shared__ unsigned short wt_lo[64 * 72];
    __shared__ float zTr[16 * 68];             // z1 row-major bounce [token][col]
    __shared__ unsigned short gbufT[64 * 32];  // [col][k] bf16, k>=16 zero
    __shared__ unsigned short sxkT[64 * 32];   // [col][k] bf16, k>=16 zero
    __shared__ unsigned short attb[2][16 * 32];// [buf][i][j] bf16, j>=16 zero
    __shared__ float pb[8 * 64];               // b1-partials [wave][col]
    __shared__ float s1p[16 * 4], s2p[16 * 4]; // z1 LN partials [row][slab-wave]
    __shared__ float s1z[16 * 4], s2z[16 * 4]; // zbar LN partials [row][slab-wave]

    // ---- init W1 as hi/lo bf16, transposed ----
    #pragma unroll
    for (int i = 0; i < 8; ++i) {
        int k = i * 8 + w;        // 0..63
        float val = W1in[(size_t)h * 4096 + (size_t)k * 64 + lane];
        unsigned short hi = f2bf(val);
        unsigned short lo = f2bf(val - b2f(hi));
        wt_hi[lane * 72 + k] = hi;
        wt_lo[lane * 72 + k] = lo;
    }
    // ---- zero pads ----
    #pragma unroll
    for (int i = 0; i < 4; ++i) { gbufT[i * 512 + t] = 0; sxkT[i * 512 + t] = 0; }
    #pragma unroll
    for (int i = 0; i < 2; ++i) ((unsigned short*)attb)[i * 512 + t] = 0;

    float b1r = b1in[h * 64 + lane];   // lane-indexed (grad phase)
    float b1c = b1in[h * 64 + gc];     // gc-indexed (A partials / zbar / D)
    float lnwr = lnw_g[h * 64 + lane];
    float lnbr = lnb_g[h * 64 + lane];
    float lnwc = lnw_g[h * 64 + gc];
    float lnbc = lnb_g[h * 64 + gc];

    const size_t gbase = ((size_t)b * Ls) * Dd + h * 64;
    const float* lrp = lrbuf + (size_t)bh * Ls;

    int ts = t & 255;
    int rowp = ts >> 4, c4p = (ts & 15) * 4;   // staging: 16 rows x 16 float4 per role
    float4 lnw4 = *(const float4*)(lnw_g + h * 64 + c4p);
    float4 lnb4 = *(const float4*)(lnb_g + h * 64 + c4p);

    // ---- prologue: step 0 staged (+fixup), prefetch step 1 (raw) ----
    float4 preq, prek, prev;
    if (role == 0) {
        float4 q0 = *(const float4*)(XQ + gbase + (size_t)rowp * Dd + c4p);
        stage_q_half(q0, &tiles[0][0][0], tbq[0], rowp, c4p);
        preq = *(const float4*)(XQ + gbase + (size_t)(16 + rowp) * Dd + c4p);
    } else {
        float4 k0 = *(const float4*)(XK + gbase + (size_t)rowp * Dd + c4p);
        float4 v0 = *(const float4*)(XV + gbase + (size_t)rowp * Dd + c4p);
        stage_kv_half(k0, v0, &tiles[0][1][0], &tiles[0][2][0], tbk[0], rowp, c4p, lnw4, lnb4);
        prek = *(const float4*)(XK + gbase + (size_t)(16 + rowp) * Dd + c4p);
        prev = *(const float4*)(XV + gbase + (size_t)(16 + rowp) * Dd + c4p);
    }
    if (t < 16) svb[0][t] = lrp[t];
    float presv = (t < 16) ? lrp[16 + t] : 0.f;
    bsync();

    const f32x4 zero4 = {0.f, 0.f, 0.f, 0.f};
    float zbar_p[4] = {0.f, 0.f, 0.f, 0.f};   // role1 deferred-D carries
    float xqc_p[4]  = {0.f, 0.f, 0.f, 0.f};

    for (int nmb = 0; nmb < NMBc; ++nmb) {
        int cb = nmb & 1, nb2 = cb ^ 1;
        int l0 = nmb * 16;
        // ---- top: stage step n+1 from prefetch regs; issue prefetch n+2 ----
        int lp = (l0 + 32 <= Ls - 16) ? (l0 + 32) : (Ls - 16);
        if (role == 0) {
            stage_q_half(preq, &tiles[nb2][0][0], tbq[nb2], rowp, c4p);
            preq = *(const float4*)(XQ + gbase + (size_t)(lp + rowp) * Dd + c4p);
        } else {
            stage_kv_half(prek, prev, &tiles[nb2][1][0], &tiles[nb2][2][0], tbk[nb2],
                          rowp, c4p, lnw4, lnb4);
            prek = *(const float4*)(XK + gbase + (size_t)(lp + rowp) * Dd + c4p);
            prev = *(const float4*)(XV + gbase + (size_t)(lp + rowp) * Dd + c4p);
        }
        if (t < 16) svb[nb2][t] = presv;
        presv = (t < 16) ? lrp[lp + t] : 0.f;

        const float* xqs = &tiles[cb][0][0];
        const float* xks = &tiles[cb][1][0];
        const float* xvs = &tiles[cb][2][0];
        const unsigned short* bqs = tbq[cb];
        const unsigned short* bks = tbk[cb];

        // ---- W1 B-frags (slab wz; read by BOTH roles; updated by role0 in C, ordered by B3) ----
        bf16x8 wh0 = *(const bf16x8*)&wt_hi[gc * 72 + 8 * q];
        bf16x8 wh1 = *(const bf16x8*)&wt_hi[gc * 72 + 32 + 8 * q];
        bf16x8 wl0 = *(const bf16x8*)&wt_lo[gc * 72 + 8 * q];
        bf16x8 wl1 = *(const bf16x8*)&wt_lo[gc * 72 + 32 + 8 * q];

        f32x4 zb = zero4;   // role1 carries zb through B1/B2
        if (role == 0) {
            // ---- Z1 slab (hi/lo split, depth 2) ----
            bf16x8 kf0 = *(const bf16x8*)&bks[n * 72 + 8 * q];
            bf16x8 kf1 = *(const bf16x8*)&bks[n * 72 + 32 + 8 * q];
            f32x4 z1 = __builtin_amdgcn_mfma_f32_16x16x32_bf16(kf0, wh0, zero4, 0, 0, 0);
            z1 = __builtin_amdgcn_mfma_f32_16x16x32_bf16(kf1, wh1, z1, 0, 0, 0);
            f32x4 z1l = __builtin_amdgcn_mfma_f32_16x16x32_bf16(kf0, wl0, zero4, 0, 0, 0);
            z1l = __builtin_amdgcn_mfma_f32_16x16x32_bf16(kf1, wl1, z1l, 0, 0, 0);
            z1 = z1 + z1l;
            // bounce row-major + z1-LN partials (zar = z1 + b1c)
            float p1[4], p2[4];
            #pragma unroll
            for (int r = 0; r < 4; ++r) {
                zTr[(4 * q + r) * 68 + gc] = z1[r];
                float za = z1[r] + b1c;
                p1[r] = rsum16(za);
                p2[r] = rsum16(za * za);
            }
            if (n < 4) {
                s1p[(4 * q + n) * 4 + wz] = sel4(n, p1[0], p1[1], p1[2], p1[3]);
                s2p[(4 * q + n) * 4 + wz] = sel4(n, p2[0], p2[1], p2[2], p2[3]);
            }
        } else {
            // ---- Zbar partial (hi/lo split, depth 2); wave 4 adds attn ----
            bf16x8 qf0 = *(const bf16x8*)&bqs[n * 72 + 8 * q];
            bf16x8 qf1 = *(const bf16x8*)&bqs[n * 72 + 32 + 8 * q];
            zb = __builtin_amdgcn_mfma_f32_16x16x32_bf16(qf0, wh0, zero4, 0, 0, 0);
            zb = __builtin_amdgcn_mfma_f32_16x16x32_bf16(qf1, wh1, zb, 0, 0, 0);
            f32x4 zbl = __builtin_amdgcn_mfma_f32_16x16x32_bf16(qf0, wl0, zero4, 0, 0, 0);
            zbl = __builtin_amdgcn_mfma_f32_16x16x32_bf16(qf1, wl1, zbl, 0, 0, 0);
            zb = zb + zbl;
            if (w == 4) {
                bf16x8 kf0 = *(const bf16x8*)&bks[n * 72 + 8 * q];
                bf16x8 kf1 = *(const bf16x8*)&bks[n * 72 + 32 + 8 * q];
                f32x4 aacc = __builtin_amdgcn_mfma_f32_16x16x32_bf16(qf1, kf1, zero4, 0, 0, 0);
                aacc = __builtin_amdgcn_mfma_f32_16x16x32_bf16(qf0, kf0, aacc, 0, 0, 0);
                float svn = svb[cb][n];
                #pragma unroll
                for (int r = 0; r < 4; ++r) {
                    int i = 4 * q + r;
                    attb[cb][i * 32 + n] = f2bf((i >= n) ? (-svn * (aacc[r] + 1.f)) : 0.f);
                }
            }
        }
        bsync(); // B1

        // ======== deferred phase D (step n-1) by role1: zbar LN + Y store ========
        if (role == 1 && nmb > 0) {
            int l0p = l0 - 16;
            #pragma unroll
            for (int r = 0; r < 4; ++r) {
                int row = 4 * q + r;
                float4 a1 = *(const float4*)&s1z[row * 4];
                float4 a2 = *(const float4*)&s2z[row * 4];
                float s1 = a1.x + a1.y + a1.z + a1.w;
                float s2 = a2.x + a2.y + a2.z + a2.w;
                float mu = s1 * (1.f / 64.f);
                float var = s2 * (1.f / 64.f) - mu * mu;
                float rstd = rsqrtf(var + 1e-6f);
                float o = lnwc * ((zbar_p[r] - mu) * rstd) + lnbc + xqc_p[r];
                Y[gbase + (size_t)(l0p + row) * Dd + gc] = o;
            }
        }

        // ======== grad phase: 2 rows per wave (rows 2w, 2w+1), lane = col ========
        float zar[2], xk_rm[2], xv_rm[2];
        #pragma unroll
        for (int r = 0; r < 2; ++r) {
            int rw = 2 * w + r;
            zar[r] = zTr[rw * 68 + lane] + b1r;
            xk_rm[r] = xks[rw * 68 + lane];
            xv_rm[r] = xvs[rw * 68 + lane];
        }
        float svr[2] = { svb[cb][2 * w], svb[cb][2 * w + 1] };
        float gr[2]; float pbv = 0.f;
        #pragma unroll
        for (int r = 0; r < 2; ++r) {
            int rw = 2 * w + r;
            float4 a1 = *(const float4*)&s1p[rw * 4];
            float4 a2 = *(const float4*)&s2p[rw * 4];
            float s1 = a1.x + a1.y + a1.z + a1.w;
            float s2 = a2.x + a2.y + a2.z + a2.w;
            float mu = s1 * (1.f / 64.f);
            float var = s2 * (1.f / 64.f) - mu * mu;
            float rstd = rsqrtf(var + 1e-6f);
            float xh = (zar[r] - mu) * rstd;
            float g = (lnwr * xh + lnbr - (xv_rm[r] - xk_rm[r])) * lnwr;
            float sg = wsum64(g);
            float sxg = wsum64(xh * g);
            gr[r] = (64.f * g - sg - xh * sxg) * rstd * (1.f / 64.f);
            pbv += svr[r] * gr[r];
        }
        {
            ushort2 gp, sp;
            gp.x = f2bf(gr[0]); gp.y = f2bf(gr[1]);
            sp.x = f2bf(svr[0] * xk_rm[0]); sp.y = f2bf(svr[1] * xk_rm[1]);
            *(ushort2*)&gbufT[lane * 32 + 2 * w] = gp;
            *(ushort2*)&sxkT[lane * 32 + 2 * w] = sp;
            pb[w * 64 + lane] = pbv;
        }
        bsync(); // B2

        // ======== C-region ========
        bf16x8 gF = *(const bf16x8*)&gbufT[gc * 32 + 8 * q];
        if (role == 0) {
            // ---- W1 update: slab wz -= (sv.xk)^T @ grad ----
            #pragma unroll
            for (int tm = 0; tm < 4; ++tm) {
                bf16x8 ax = *(const bf16x8*)&sxkT[(16 * tm + n) * 32 + 8 * q];
                f32x4 dl = __builtin_amdgcn_mfma_f32_16x16x32_bf16(ax, gF, zero4, 0, 0, 0);
                int ko = 16 * tm + 4 * q;
                ushort4 h4 = *(ushort4*)&wt_hi[gc * 72 + ko];
                ushort4 l4 = *(ushort4*)&wt_lo[gc * 72 + ko];
                float w0 = b2f(h4.x) + b2f(l4.x) - dl[0];
                float w1 = b2f(h4.y) + b2f(l4.y) - dl[1];
                float w2 = b2f(h4.z) + b2f(l4.z) - dl[2];
                float w3 = b2f(h4.w) + b2f(l4.w) - dl[3];
                h4.x = f2bf(w0); l4.x = f2bf(w0 - b2f(h4.x));
                h4.y = f2bf(w1); l4.y = f2bf(w1 - b2f(h4.y));
                h4.z = f2bf(w2); l4.z = f2bf(w2 - b2f(h4.z));
                h4.w = f2bf(w3); l4.w = f2bf(w3 - b2f(h4.w));
                *(ushort4*)&wt_hi[gc * 72 + ko] = h4;
                *(ushort4*)&wt_lo[gc * 72 + ko] = l4;
            }
        } else {
            // ---- Zbar finish + LN partials + xq carry (uses OLD b1c) ----
            bf16x8 amF = *(const bf16x8*)&attb[cb][n * 32 + 8 * q];
            zb = __builtin_amdgcn_mfma_f32_16x16x32_bf16(amF, gF, zb, 0, 0, 0);
            float pz1[4], pz2[4];
            #pragma unroll
            for (int r = 0; r < 4; ++r) {
                zbar_p[r] = zb[r] + b1c;
                pz1[r] = rsum16(zbar_p[r]);
                pz2[r] = rsum16(zbar_p[r] * zbar_p[r]);
                xqc_p[r] = xqs[(4 * q + r) * 68 + gc];   // safe: tile[cb] overwritten at top(n+2)
            }
            if (n < 4) {
                s1z[(4 * q + n) * 4 + wz] = sel4(n, pz1[0], pz1[1], pz1[2], pz1[3]);
                s2z[(4 * q + n) * 4 + wz] = sel4(n, pz2[0], pz2[1], pz2[2], pz2[3]);
            }
        }
        // ---- b1 updates (old values used above) ----
        {
            float sbr = 0.f, sbc = 0.f;
            #pragma unroll
            for (int i = 0; i < 8; ++i) { sbr += pb[i * 64 + lane]; sbc += pb[i * 64 + gc]; }
            b1r -= sbr; b1c -= sbc;
        }
        bsync(); // B3 (W1 slab + s1z/s2z ready for next step's readers)
    }

    // ---- epilogue: flush deferred phase D for step NMBc-1 (role1) ----
    if (role == 1) {
        int l0p = (NMBc - 1) * 16;
        #pragma unroll
        for (int r = 0; r < 4; ++r) {
            int row = 4 * q + r;
            float4 a1 = *(const float4*)&s1z[row * 4];
            float4 a2 = *(const float4*)&s2z[row * 4];
            float s1 = a1.x + a1.y + a1.z + a1.w;
            float s2 = a2.x + a2.y + a2.z + a2.w;
            float mu = s1 * (1.f / 64.f);
            float var = s2 * (1.f / 64.f) - mu * mu;
            float rstd = rsqrtf(var + 1e-6f);
            float o = lnwc * ((zbar_p[r] - mu) * rstd) + lnbc + xqc_p[r];
            Y[gbase + (size_t)(l0p + row) * Dd + gc] = o;
        }
    }
}

// ---------------- post layernorm over D + cast to bf16 ----------------
__global__ __launch_bounds__(256) void postnorm_kernel(const float* __restrict__ Y,
                                                       const float* __restrict__ pw,
                                                       const float* __restrict__ pb,
                                                       unsigned short* __restrict__ Yb) {
    int tok = blockIdx.x, t = threadIdx.x;
    const float* row = Y + (size_t)tok * Dd;
    int c0 = t * 4, c1 = 1024 + t * 4;
    float4 v0 = *(const float4*)(row + c0);
    float4 v1 = *(const float4*)(row + c1);
    float s1 = v0.x + v0.y + v0.z + v0.w + v1.x + v1.y + v1.z + v1.w;
    float s2 = v0.x * v0.x + v0.y * v0.y + v0.z * v0.z + v0.w * v0.w +
               v1.x * v1.x + v1.y * v1.y + v1.z * v1.z + v1.w * v1.w;
    s1 = wsum64(s1); s2 = wsum64(s2);
    __shared__ float r1[4], r2[4];
    if ((t & 63) == 0) { r1[t >> 6] = s1; r2[t >> 6] = s2; }
    __syncthreads();
    float S1 = r1[0] + r1[1] + r1[2] + r1[3];
    float S2 = r2[0] + r2[1] + r2[2] + r2[3];
    float mu = S1 * (1.f / 2048.f);
    float var = S2 * (1.f / 2048.f) - mu * mu;
    float rstd = rsqrtf(var + 1e-6f);
    float4 w0 = *(const float4*)(pw + c0), b0 = *(const float4*)(pb + c0);
    float4 w1 = *(const float4*)(pw + c1), b1 = *(const float4*)(pb + c1);
    ushort4 o0, o1;
    o0.x = f2bf((v0.x - mu) * rstd * w0.x + b0.x);
    o0.y = f2bf((v0.y - mu) * rstd * w0.y + b0.y);
    o0.z = f2bf((v0.z - mu) * rstd * w0.z + b0.z);
    o0.w = f2bf((v0.w - mu) * rstd * w0.w + b0.w);
    o1.x = f2bf((v1.x - mu) * rstd * w1.x + b1.x);
    o1.y = f2bf((v1.y - mu) * rstd * w1.y + b1.y);
    o1.z = f2bf((v1.z - mu) * rstd * w1.z + b1.z);
    o1.w = f2bf((v1.w - mu) * rstd * w1.w + b1.w);
    *(ushort4*)(Yb + (size_t)tok * Dd + c0) = o0;
    *(ushort4*)(Yb + (size_t)tok * Dd + c1) = o1;
}

extern "C" void kernel_launch(void* const* d_in, const int* in_sizes, int n_in,
                              void* d_out, int out_size, void* d_ws, size_t ws_size,
                              hipStream_t stream) {
    const float* hs   = (const float*)d_in[0];
    const float* wq_w = (const float*)d_in[1];
    const float* wq_b = (const float*)d_in[2];
    const float* wk_w = (const float*)d_in[3];
    const float* wk_b = (const float*)d_in[4];
    const float* wv_w = (const float*)d_in[5];
    const float* wv_b = (const float*)d_in[6];
    const float* wo_w = (const float*)d_in[7];
    const float* wo_b = (const float*)d_in[8];
    const float* lnw  = (const float*)d_in[9];
    const float* lnb  = (const float*)d_in[10];
    const float* lr_w = (const float*)d_in[11];
    const float* lr_b = (const float*)d_in[12];
    const float* W1   = (const float*)d_in[13];
    const float* b1   = (const float*)d_in[14];
    const float* pnw  = (const float*)d_in[15];
    const float* pnb  = (const float*)d_in[16];
    float* out = (float*)d_out;

    char* ws = (char*)d_ws;
    size_t off = 0;
    auto alloc = [&](size_t bytes) -> void* {
        void* p = ws + off; off += (bytes + 255) & ~(size_t)255; return p;
    };
    unsigned short* hsb = (unsigned short*)alloc((size_t)MTOK * Dd * 2);
    unsigned short* wtb = (unsigned short*)alloc((size_t)Dd * Dd * 2);
    float* XQ = (float*)alloc((size_t)MTOK * Dd * 4);
    float* XK = (float*)alloc((size_t)MTOK * Dd * 4);
    float* XV = (float*)alloc((size_t)MTOK * Dd * 4);
    float* lrbuf = (float*)alloc((size_t)Bb * Hh * Ls * 4);
    float* Y = XQ;                 // safe alias (per-chain row/col ownership; writes trail reads)
    unsigned short* Yb = hsb;      // hsb dead after QKV GEMMs

    dim3 blk(256);
    cast_hs_kernel<<<dim3(MTOK * Dd / 1024), blk, 0, stream>>>(hs, hsb);

    transpose_cast_kernel<<<dim3(1024), blk, 0, stream>>>(wq_w, wtb);
    gemm_bt_kernel<<<dim3(64, 16), blk, 0, stream>>>(hsb, wtb, wq_b, XQ, MTOK, Dd, Dd);
    transpose_cast_kernel<<<dim3(1024), blk, 0, stream>>>(wk_w, wtb);
    gemm_bt_kernel<<<dim3(64, 16), blk, 0, stream>>>(hsb, wtb, wk_b, XK, MTOK, Dd, Dd);
    transpose_cast_kernel<<<dim3(1024), blk, 0, stream>>>(wv_w, wtb);
    gemm_bt_kernel<<<dim3(64, 16), blk, 0, stream>>>(hsb, wtb, wv_b, XV, MTOK, Dd, Dd);

    lr_kernel<<<dim3(MTOK), blk, 0, stream>>>(hs, lr_w, lr_b, lrbuf);

    scan_kernel<<<dim3(Bb * Hh), dim3(512), 0, stream>>>(XQ, XK, XV, lrbuf, W1, b1, lnw, lnb, Y);

    postnorm_kernel<<<dim3(MTOK), blk, 0, stream>>>(Y, pnw, pnb, Yb);

    transpose_cast_kernel<<<dim3(1024), blk, 0, stream>>>(wo_w, wtb);
    gemm_bt_kernel<<<dim3(64, 16), blk, 0, stream>>>(Yb, wtb, wo_b, out, MTOK, Dd, Dd);
}

// Round 8
// 1320.154 us; speedup vs baseline: 1.0965x; 1.0616x over previous
//
#include <hip/hip_runtime.h>
#include <hip/hip_bf16.h>
#include <cstdint>
#include <cstddef>

#define DEV __device__ __forceinline__

constexpr int Bb = 2, Ls = 4096, Dd = 2048, Hh = 32, HD = 64, MBK = 16, NMBc = 256;
constexpr int MTOK = Bb * Ls; // 8192 tokens

typedef __bf16 bf16x8 __attribute__((ext_vector_type(8)));
typedef float  f32x4  __attribute__((ext_vector_type(4)));

// hardware RNE f32->bf16
DEV unsigned short f2bf(float f) {
    union { __bf16 h; unsigned short u; } x;
    x.h = (__bf16)f;
    return x.u;
}
DEV float b2f(unsigned short u) {
    union { unsigned int i; float f; } x; x.i = ((unsigned int)u) << 16;
    return x.f;
}

// LDS-only barrier (T4): drain ONLY lgkmcnt, raw s_barrier, leave vmcnt in flight.
DEV void bsync() {
    asm volatile("s_waitcnt lgkmcnt(0)" ::: "memory");
    __builtin_amdgcn_s_barrier();
    asm volatile("" ::: "memory");
}

// 64-lane sum via DPP; lane 63 holds total, readlane broadcasts (uniform use).
DEV float wsum64(float v) {
    int t;
    t = __builtin_amdgcn_update_dpp(0, __float_as_int(v), 0x111, 0xf, 0xf, true); v += __int_as_float(t);
    t = __builtin_amdgcn_update_dpp(0, __float_as_int(v), 0x112, 0xf, 0xf, true); v += __int_as_float(t);
    t = __builtin_amdgcn_update_dpp(0, __float_as_int(v), 0x114, 0xf, 0xf, true); v += __int_as_float(t);
    t = __builtin_amdgcn_update_dpp(0, __float_as_int(v), 0x118, 0xf, 0xf, true); v += __int_as_float(t);
    t = __builtin_amdgcn_update_dpp(0, __float_as_int(v), 0x142, 0xa, 0xf, true); v += __int_as_float(t);
    t = __builtin_amdgcn_update_dpp(0, __float_as_int(v), 0x143, 0xc, 0xf, true); v += __int_as_float(t);
    return __int_as_float(__builtin_amdgcn_readlane(__float_as_int(v), 63));
}

// 16-lane (DPP row) rotate-reduce sum.
DEV float rsum16(float v) {
    int t;
    t = __builtin_amdgcn_update_dpp(0, __float_as_int(v), 0x121, 0xf, 0xf, true); v += __int_as_float(t);
    t = __builtin_amdgcn_update_dpp(0, __float_as_int(v), 0x122, 0xf, 0xf, true); v += __int_as_float(t);
    t = __builtin_amdgcn_update_dpp(0, __float_as_int(v), 0x124, 0xf, 0xf, true); v += __int_as_float(t);
    t = __builtin_amdgcn_update_dpp(0, __float_as_int(v), 0x128, 0xf, 0xf, true); v += __int_as_float(t);
    return v;
}

// runtime-n select from 4 scalars (no dynamic indexing -> no scratch)
DEV float sel4(int n, float a, float b, float c, float d) {
    float v = (n == 1) ? b : a;
    v = (n == 2) ? c : v;
    v = (n == 3) ? d : v;
    return v;
}

DEV void g2l16(const void* g, void* l) {
    __builtin_amdgcn_global_load_lds(
        (__attribute__((address_space(1))) void*)(g),
        (__attribute__((address_space(3))) void*)(l), 16, 0, 0);
}

// ---------------- cast hidden_states fp32 -> bf16 ----------------
__global__ __launch_bounds__(256) void cast_hs_kernel(const float* __restrict__ src,
                                                      unsigned short* __restrict__ dst) {
    int i = (blockIdx.x * 256 + threadIdx.x) * 4;
    float4 v = *(const float4*)(src + i);
    ushort4 o; o.x = f2bf(v.x); o.y = f2bf(v.y); o.z = f2bf(v.z); o.w = f2bf(v.w);
    *(ushort4*)(dst + i) = o;
}

// ---------------- transpose + cast weight: W[k][n] fp32 -> Wt[n][k] bf16 ----------------
__global__ __launch_bounds__(256) void transpose_cast_kernel(const float* __restrict__ W,
                                                             unsigned short* __restrict__ Wt) {
    __shared__ float tile[64][65];
    int bx = blockIdx.x & 31;   // k-tile
    int by = blockIdx.x >> 5;   // n-tile
    int t = threadIdx.x;
    int r = t >> 4, c4 = (t & 15) * 4;
    #pragma unroll
    for (int i = 0; i < 4; ++i) {
        int row = r + i * 16;
        float4 v = *(const float4*)(W + (size_t)(bx * 64 + row) * Dd + by * 64 + c4);
        tile[row][c4 + 0] = v.x; tile[row][c4 + 1] = v.y;
        tile[row][c4 + 2] = v.z; tile[row][c4 + 3] = v.w;
    }
    __syncthreads();
    #pragma unroll
    for (int i = 0; i < 4; ++i) {
        int row = r + i * 16; // n index
        ushort4 o;
        o.x = f2bf(tile[c4 + 0][row]); o.y = f2bf(tile[c4 + 1][row]);
        o.z = f2bf(tile[c4 + 2][row]); o.w = f2bf(tile[c4 + 3][row]);
        *(ushort4*)(Wt + (size_t)(by * 64 + row) * Dd + bx * 64 + c4) = o;
    }
}

// ---------------- 256x256 8-phase bf16 MFMA GEMM (T1+T2+T3+T4+T5) ----------------
// C[M,N] = A[M,K] @ Bt[N,K]^T + bias.  8 waves (2M x 4N), BK=64, 128 KiB LDS
// (2 bufs x {A 256x64, B 256x64} bf16). Per K-tile group: 4 phases, each
// {ds-read frag subtile | stage 1 half-tile (2 x global_load_lds) | barrier |
//  lgkmcnt(0) | setprio(1) 16 MFMA setprio(0) | barrier}; counted vmcnt(4)
// only at group boundaries (3-4 half-tiles stay in flight across barriers).
// LDS XOR swizzle: col-chunk ^ (row&7) on BOTH the staged global source and
// the ds_read address (same involution). XCD-bijective block swizzle (grid%8==0).
__global__ __launch_bounds__(512, 2) void gemm256_kernel(const unsigned short* __restrict__ A,
                                                         const unsigned short* __restrict__ Bt,
                                                         const float* __restrict__ bias,
                                                         float* __restrict__ C,
                                                         int M, int N, int Kd) {
    __shared__ unsigned short sA[2][256 * 64];
    __shared__ unsigned short sB[2][256 * 64];
    int t = threadIdx.x;
    int lane = t & 63;
    int wid = t >> 6;                 // 0..7
    int wm = wid >> 2, wn = wid & 3;  // 2 M-waves x 4 N-waves
    int q = lane >> 4, n = lane & 15;

    // XCD-aware bijective swizzle (gridDim.x divisible by 8)
    int cpx = gridDim.x >> 3;
    int swz = (blockIdx.x & 7) * cpx + (blockIdx.x >> 3);
    int nbn = N >> 8;
    int bm = swz / nbn, bn = swz % nbn;

    // staging geometry: half-tile = 128 rows x 64 cols bf16 = 16KB = 512 thr x 16B x 2
    // chunk c = j*512 + t: row r=c>>3, col-chunk c&7; global col-chunk pre-swizzled.
    int r0 = t >> 3;                    // j=0 row (0..63); j=1 row = r0+64
    int kc = (t & 7) ^ (r0 & 7);        // same for both j (row&7 identical)
    int lo0 = t * 8;                    // LDS element offset j=0 (lane-linear)
    const unsigned short* gA = A + (size_t)(bm * 256) * Kd;
    const unsigned short* gB = Bt + (size_t)(bn * 256) * Kd;

    auto stageA = [&](int buf, int half, int kt) {
        const unsigned short* s0 = gA + (size_t)(half * 128 + r0) * Kd + kt * 64 + kc * 8;
        const unsigned short* s1 = gA + (size_t)(half * 128 + 64 + r0) * Kd + kt * 64 + kc * 8;
        g2l16(s0, &sA[buf][half * 8192 + lo0]);
        g2l16(s1, &sA[buf][half * 8192 + 4096 + lo0]);
    };
    auto stageB = [&](int buf, int half, int kt) {
        const unsigned short* s0 = gB + (size_t)(half * 128 + r0) * Kd + kt * 64 + kc * 8;
        const unsigned short* s1 = gB + (size_t)(half * 128 + 64 + r0) * Kd + kt * 64 + kc * 8;
        g2l16(s0, &sB[buf][half * 8192 + lo0]);
        g2l16(s1, &sB[buf][half * 8192 + 4096 + lo0]);
    };

    f32x4 acc[8][4];
    #pragma unroll
    for (int i = 0; i < 8; ++i)
        #pragma unroll
        for (int j = 0; j < 4; ++j)
            #pragma unroll
            for (int r = 0; r < 4; ++r) acc[i][j][r] = 0.f;

    int nkt = Kd >> 6;   // K-tiles of 64

    // ---- prologue: A(0),B(0) + B(1); wait for first 8 loads (A0+B0) ----
    stageA(0, 0, 0); stageA(0, 1, 0);
    stageB(0, 0, 0); stageB(0, 1, 0);
    stageB(1, 0, 1); stageB(1, 1, 1);
    asm volatile("s_waitcnt vmcnt(4)" ::: "memory");
    __builtin_amdgcn_s_barrier();
    asm volatile("" ::: "memory");

    for (int G = 0; G < nkt; ++G) {
        int cur = G & 1;
        const unsigned short* bA = sA[cur];
        const unsigned short* bB = sB[cur];
        bf16x8 bfv[4][2];
        #pragma unroll
        for (int p = 0; p < 4; ++p) {
            // ---- ds-read frag subtile ----
            bf16x8 af[2][2];
            #pragma unroll
            for (int mi = 0; mi < 2; ++mi) {
                int row = wm * 128 + (2 * p + mi) * 16 + n;
                #pragma unroll
                for (int kk = 0; kk < 2; ++kk)
                    af[mi][kk] = *(const bf16x8*)&bA[row * 64 + (((kk * 4 + q) ^ (n & 7)) * 8)];
            }
            if (p == 0) {
                #pragma unroll
                for (int nt = 0; nt < 4; ++nt) {
                    int row = wn * 64 + nt * 16 + n;
                    #pragma unroll
                    for (int kk = 0; kk < 2; ++kk)
                        bfv[nt][kk] = *(const bf16x8*)&bB[row * 64 + (((kk * 4 + q) ^ (n & 7)) * 8)];
                }
            }
            // ---- stage 1 half-tile (regions freed in strictly earlier phases) ----
            if (p == 0) { if (G + 1 < nkt) stageA(cur ^ 1, 0, G + 1); }
            if (p == 1) { if (G + 1 < nkt) stageA(cur ^ 1, 1, G + 1); }
            if (p == 2) { if (G + 2 < nkt) stageB(cur, 0, G + 2); }
            if (p == 3) { if (G + 2 < nkt) stageB(cur, 1, G + 2); }

            asm volatile("" ::: "memory");
            __builtin_amdgcn_s_barrier();
            asm volatile("s_waitcnt lgkmcnt(0)" ::: "memory");
            __builtin_amdgcn_sched_barrier(0);
            __builtin_amdgcn_s_setprio(1);
            #pragma unroll
            for (int mi = 0; mi < 2; ++mi)
                #pragma unroll
                for (int nt = 0; nt < 4; ++nt)
                    acc[2 * p + mi][nt] = __builtin_amdgcn_mfma_f32_16x16x32_bf16(
                        af[mi][0], bfv[nt][0], acc[2 * p + mi][nt], 0, 0, 0);
            #pragma unroll
            for (int mi = 0; mi < 2; ++mi)
                #pragma unroll
                for (int nt = 0; nt < 4; ++nt)
                    acc[2 * p + mi][nt] = __builtin_amdgcn_mfma_f32_16x16x32_bf16(
                        af[mi][1], bfv[nt][1], acc[2 * p + mi][nt], 0, 0, 0);
            __builtin_amdgcn_s_setprio(0);
            if (p == 3) {
                // group boundary: next K-tile's A+B must have landed.
                if (G + 2 >= nkt) asm volatile("s_waitcnt vmcnt(0)" ::: "memory");
                else              asm volatile("s_waitcnt vmcnt(4)" ::: "memory");
            }
            asm volatile("" ::: "memory");
            __builtin_amdgcn_s_barrier();
            asm volatile("" ::: "memory");
        }
    }

    // ---- epilogue: bias + store ----
    float bv[4];
    #pragma unroll
    for (int nt = 0; nt < 4; ++nt) bv[nt] = bias[bn * 256 + wn * 64 + nt * 16 + n];
    #pragma unroll
    for (int m = 0; m < 8; ++m)
        #pragma unroll
        for (int r = 0; r < 4; ++r) {
            int row = bm * 256 + wm * 128 + m * 16 + 4 * q + r;
            float* cp = C + (size_t)row * N + bn * 256 + wn * 64 + n;
            #pragma unroll
            for (int nt = 0; nt < 4; ++nt) cp[nt * 16] = acc[m][nt][r] + bv[nt];
        }
}

// ---------------- lr: s[b,h,l] = sigmoid(hs[b,l,:]·lr_w[h,:] + lr_b[h]) / (HD*K) ----------------
__global__ __launch_bounds__(256) void lr_kernel(const float* __restrict__ hs,
                                                 const float* __restrict__ lrw,
                                                 const float* __restrict__ lrb,
                                                 float* __restrict__ lr_out) {
    int tok = blockIdx.x; // b*L + l
    int t = threadIdx.x;
    int h = t >> 3, j0 = t & 7;
    const float* row = hs + (size_t)tok * Dd;
    const float* wr = lrw + (size_t)h * Dd;
    float p = 0.f;
    for (int j = j0 * 4; j < Dd; j += 32) {
        float4 a = *(const float4*)(row + j);
        float4 w = *(const float4*)(wr + j);
        p += a.x * w.x + a.y * w.y + a.z * w.z + a.w * w.w;
    }
    __shared__ float red[32][8];
    red[h][j0] = p;
    __syncthreads();
    if (t < 32) {
        float s = 0.f;
        #pragma unroll
        for (int i = 0; i < 8; ++i) s += red[t][i];
        s += lrb[t];
        s = 1.f / (1.f + expf(-s));
        s *= 1.0f / (HD * MBK);
        int b = tok >> 12, l = tok & (Ls - 1);
        lr_out[(size_t)(b * Hh + t) * Ls + l] = s;
    }
}

// staging helpers (role-split): 16 rows x 16 float4 per role group of 256 threads
DEV void stage_q_half(float4 q, float* tq, unsigned short* bq, int rowp, int c4p) {
    float rq = 1.f / fmaxf(sqrtf(rsum16(q.x*q.x + q.y*q.y + q.z*q.z + q.w*q.w)), 1e-12f);
    q.x *= rq; q.y *= rq; q.z *= rq; q.w *= rq;
    *(float4*)&tq[rowp * 68 + c4p] = q;
    ushort4 qb;
    qb.x = f2bf(q.x); qb.y = f2bf(q.y); qb.z = f2bf(q.z); qb.w = f2bf(q.w);
    *(ushort4*)&bq[rowp * 72 + c4p] = qb;
}
DEV void stage_kv_half(float4 k, float4 v, float* tk, float* tv, unsigned short* bk,
                       int rowp, int c4p, float4 lnw4, float4 lnb4) {
    float rk = 1.f / fmaxf(sqrtf(rsum16(k.x*k.x + k.y*k.y + k.z*k.z + k.w*k.w)), 1e-12f);
    k.x *= rk; k.y *= rk; k.z *= rk; k.w *= rk;
    float4 df; df.x = v.x - k.x; df.y = v.y - k.y; df.z = v.z - k.z; df.w = v.w - k.w;
    float mu = rsum16(df.x + df.y + df.z + df.w) * (1.f / 64.f);
    float4 cc; cc.x = df.x - mu; cc.y = df.y - mu; cc.z = df.z - mu; cc.w = df.w - mu;
    float var = rsum16(cc.x*cc.x + cc.y*cc.y + cc.z*cc.z + cc.w*cc.w) * (1.f / 63.f); // ddof=1
    float rs = 1.f / (sqrtf(var) + 1e-8f);
    float4 vn;
    vn.x = lnw4.x * cc.x * rs + lnb4.x + k.x;
    vn.y = lnw4.y * cc.y * rs + lnb4.y + k.y;
    vn.z = lnw4.z * cc.z * rs + lnb4.z + k.z;
    vn.w = lnw4.w * cc.w * rs + lnb4.w + k.w;
    *(float4*)&tk[rowp * 68 + c4p] = k;
    *(float4*)&tv[rowp * 68 + c4p] = vn;
    ushort4 kb;
    kb.x = f2bf(k.x); kb.y = f2bf(k.y); kb.z = f2bf(k.z); kb.w = f2bf(k.w);
    *(ushort4*)&bk[rowp * 72 + c4p] = kb;
}

// ---------------- MFMA TTT scan: 8 waves per (b,h) chain (role split) ----------------
__global__ __launch_bounds__(512, 1) void scan_kernel(const float* __restrict__ XQ,
                                                      const float* __restrict__ XK,
                                                      const float* __restrict__ XV,
                                                      const float* __restrict__ lrbuf,
                                                      const float* __restrict__ W1in,
                                                      const float* __restrict__ b1in,
                                                      const float* __restrict__ lnw_g,
                                                      const float* __restrict__ lnb_g,
                                                      float* __restrict__ Y) {
    int bh = blockIdx.x;          // b*H + h
    int b = bh >> 5, h = bh & 31;
    int t = threadIdx.x;
    int w = t >> 6;               // wave 0..7
    int lane = t & 63;
    int q = lane >> 4, n = lane & 15;
    int role = w >> 2, wz = w & 3;
    int gc = 16 * wz + n;         // this lane's C-layout global column (slab wz)

    __shared__ float tiles[2][3][16 * 68];     // [buf][xq,xk,xv][token][feat] fp32
    __shared__ unsigned short tbq[2][16 * 72]; // bf16 xq tiles
    __shared__ unsigned short tbk[2][16 * 72]; // bf16 xk tiles
    __shared__ float svb[2][16];
    __shared__ unsigned short wt_hi[64 * 72];  // [col][k]
    __shared__ unsigned short wt_lo[64 * 72];
    __shared__ float zTr[16 * 68];             // z1 row-major bounce [token][col]
    __shared__ unsigned short gbufT[64 * 32];  // [col][k] bf16, k>=16 zero
    __shared__ unsigned short sxkT[64 * 32];   // [col][k] bf16, k>=16 zero
    __shared__ unsigned short attb[2][16 * 32];// [buf][i][j] bf16, j>=16 zero
    __shared__ float pb[8 * 64];               // b1-partials [wave][col]
    __shared__ float s1p[16 * 4], s2p[16 * 4]; // z1 LN partials [row][slab-wave]
    __shared__ float s1z[16 * 4], s2z[16 * 4]; // zbar LN partials [row][slab-wave]

    // ---- init W1 as hi/lo bf16, transposed ----
    #pragma unroll
    for (int i = 0; i < 8; ++i) {
        int k = i * 8 + w;        // 0..63
        float val = W1in[(size_t)h * 4096 + (size_t)k * 64 + lane];
        unsigned short hi = f2bf(val);
        unsigned short lo = f2bf(val - b2f(hi));
        wt_hi[lane * 72 + k] = hi;
        wt_lo[lane * 72 + k] = lo;
    }
    // ---- zero pads ----
    #pragma unroll
    for (int i = 0; i < 4; ++i) { gbufT[i * 512 + t] = 0; sxkT[i * 512 + t] = 0; }
    #pragma unroll
    for (int i = 0; i < 2; ++i) ((unsigned short*)attb)[i * 512 + t] = 0;

    float b1r = b1in[h * 64 + lane];   // lane-indexed (grad phase)
    float b1c = b1in[h * 64 + gc];     // gc-indexed (A partials / zbar / D)
    float lnwr = lnw_g[h * 64 + lane];
    float lnbr = lnb_g[h * 64 + lane];
    float lnwc = lnw_g[h * 64 + gc];
    float lnbc = lnb_g[h * 64 + gc];

    const size_t gbase = ((size_t)b * Ls) * Dd + h * 64;
    const float* lrp = lrbuf + (size_t)bh * Ls;

    int ts = t & 255;
    int rowp = ts >> 4, c4p = (ts & 15) * 4;   // staging: 16 rows x 16 float4 per role
    float4 lnw4 = *(const float4*)(lnw_g + h * 64 + c4p);
    float4 lnb4 = *(const float4*)(lnb_g + h * 64 + c4p);

    // ---- prologue: step 0 staged (+fixup), prefetch step 1 (raw) ----
    float4 preq, prek, prev;
    if (role == 0) {
        float4 q0 = *(const float4*)(XQ + gbase + (size_t)rowp * Dd + c4p);
        stage_q_half(q0, &tiles[0][0][0], tbq[0], rowp, c4p);
        preq = *(const float4*)(XQ + gbase + (size_t)(16 + rowp) * Dd + c4p);
    } else {
        float4 k0 = *(const float4*)(XK + gbase + (size_t)rowp * Dd + c4p);
        float4 v0 = *(const float4*)(XV + gbase + (size_t)rowp * Dd + c4p);
        stage_kv_half(k0, v0, &tiles[0][1][0], &tiles[0][2][0], tbk[0], rowp, c4p, lnw4, lnb4);
        prek = *(const float4*)(XK + gbase + (size_t)(16 + rowp) * Dd + c4p);
        prev = *(const float4*)(XV + gbase + (size_t)(16 + rowp) * Dd + c4p);
    }
    if (t < 16) svb[0][t] = lrp[t];
    float presv = (t < 16) ? lrp[16 + t] : 0.f;
    bsync();

    const f32x4 zero4 = {0.f, 0.f, 0.f, 0.f};
    float zbar_p[4] = {0.f, 0.f, 0.f, 0.f};   // role1 deferred-D carries
    float xqc_p[4]  = {0.f, 0.f, 0.f, 0.f};

    for (int nmb = 0; nmb < NMBc; ++nmb) {
        int cb = nmb & 1, nb2 = cb ^ 1;
        int l0 = nmb * 16;
        // ---- top: stage step n+1 from prefetch regs; issue prefetch n+2 ----
        int lp = (l0 + 32 <= Ls - 16) ? (l0 + 32) : (Ls - 16);
        if (role == 0) {
            stage_q_half(preq, &tiles[nb2][0][0], tbq[nb2], rowp, c4p);
            preq = *(const float4*)(XQ + gbase + (size_t)(lp + rowp) * Dd + c4p);
        } else {
            stage_kv_half(prek, prev, &tiles[nb2][1][0], &tiles[nb2][2][0], tbk[nb2],
                          rowp, c4p, lnw4, lnb4);
            prek = *(const float4*)(XK + gbase + (size_t)(lp + rowp) * Dd + c4p);
            prev = *(const float4*)(XV + gbase + (size_t)(lp + rowp) * Dd + c4p);
        }
        if (t < 16) svb[nb2][t] = presv;
        presv = (t < 16) ? lrp[lp + t] : 0.f;

        const float* xqs = &tiles[cb][0][0];
        const float* xks = &tiles[cb][1][0];
        const float* xvs = &tiles[cb][2][0];
        const unsigned short* bqs = tbq[cb];
        const unsigned short* bks = tbk[cb];

        // ---- W1 B-frags (slab wz; updated by role0 in C, ordered by B3) ----
        bf16x8 wh0 = *(const bf16x8*)&wt_hi[gc * 72 + 8 * q];
        bf16x8 wh1 = *(const bf16x8*)&wt_hi[gc * 72 + 32 + 8 * q];
        bf16x8 wl0 = *(const bf16x8*)&wt_lo[gc * 72 + 8 * q];
        bf16x8 wl1 = *(const bf16x8*)&wt_lo[gc * 72 + 32 + 8 * q];

        f32x4 zb = zero4;   // role1 carries zb through B1/B2
        if (role == 0) {
            bf16x8 kf0 = *(const bf16x8*)&bks[n * 72 + 8 * q];
            bf16x8 kf1 = *(const bf16x8*)&bks[n * 72 + 32 + 8 * q];
            f32x4 z1 = __builtin_amdgcn_mfma_f32_16x16x32_bf16(kf0, wh0, zero4, 0, 0, 0);
            z1 = __builtin_amdgcn_mfma_f32_16x16x32_bf16(kf1, wh1, z1, 0, 0, 0);
            f32x4 z1l = __builtin_amdgcn_mfma_f32_16x16x32_bf16(kf0, wl0, zero4, 0, 0, 0);
            z1l = __builtin_amdgcn_mfma_f32_16x16x32_bf16(kf1, wl1, z1l, 0, 0, 0);
            z1 = z1 + z1l;
            float p1[4], p2[4];
            #pragma unroll
            for (int r = 0; r < 4; ++r) {
                zTr[(4 * q + r) * 68 + gc] = z1[r];
                float za = z1[r] + b1c;
                p1[r] = rsum16(za);
                p2[r] = rsum16(za * za);
            }
            if (n < 4) {
                s1p[(4 * q + n) * 4 + wz] = sel4(n, p1[0], p1[1], p1[2], p1[3]);
                s2p[(4 * q + n) * 4 + wz] = sel4(n, p2[0], p2[1], p2[2], p2[3]);
            }
        } else {
            bf16x8 qf0 = *(const bf16x8*)&bqs[n * 72 + 8 * q];
            bf16x8 qf1 = *(const bf16x8*)&bqs[n * 72 + 32 + 8 * q];
            zb = __builtin_amdgcn_mfma_f32_16x16x32_bf16(qf0, wh0, zero4, 0, 0, 0);
            zb = __builtin_amdgcn_mfma_f32_16x16x32_bf16(qf1, wh1, zb, 0, 0, 0);
            f32x4 zbl = __builtin_amdgcn_mfma_f32_16x16x32_bf16(qf0, wl0, zero4, 0, 0, 0);
            zbl = __builtin_amdgcn_mfma_f32_16x16x32_bf16(qf1, wl1, zbl, 0, 0, 0);
            zb = zb + zbl;
            if (w == 4) {
                bf16x8 kf0 = *(const bf16x8*)&bks[n * 72 + 8 * q];
                bf16x8 kf1 = *(const bf16x8*)&bks[n * 72 + 32 + 8 * q];
                f32x4 aacc = __builtin_amdgcn_mfma_f32_16x16x32_bf16(qf1, kf1, zero4, 0, 0, 0);
                aacc = __builtin_amdgcn_mfma_f32_16x16x32_bf16(qf0, kf0, aacc, 0, 0, 0);
                float svn = svb[cb][n];
                #pragma unroll
                for (int r = 0; r < 4; ++r) {
                    int i = 4 * q + r;
                    attb[cb][i * 32 + n] = f2bf((i >= n) ? (-svn * (aacc[r] + 1.f)) : 0.f);
                }
            }
        }
        bsync(); // B1

        // ======== deferred phase D (step n-1) by role1: zbar LN + Y store ========
        if (role == 1 && nmb > 0) {
            int l0p = l0 - 16;
            #pragma unroll
            for (int r = 0; r < 4; ++r) {
                int row = 4 * q + r;
                float4 a1 = *(const float4*)&s1z[row * 4];
                float4 a2 = *(const float4*)&s2z[row * 4];
                float s1 = a1.x + a1.y + a1.z + a1.w;
                float s2 = a2.x + a2.y + a2.z + a2.w;
                float mu = s1 * (1.f / 64.f);
                float var = s2 * (1.f / 64.f) - mu * mu;
                float rstd = rsqrtf(var + 1e-6f);
                float o = lnwc * ((zbar_p[r] - mu) * rstd) + lnbc + xqc_p[r];
                Y[gbase + (size_t)(l0p + row) * Dd + gc] = o;
            }
        }

        // ======== grad phase: 2 rows per wave (rows 2w, 2w+1), lane = col ========
        float zar[2], xk_rm[2], xv_rm[2];
        #pragma unroll
        for (int r = 0; r < 2; ++r) {
            int rw = 2 * w + r;
            zar[r] = zTr[rw * 68 + lane] + b1r;
            xk_rm[r] = xks[rw * 68 + lane];
            xv_rm[r] = xvs[rw * 68 + lane];
        }
        float svr[2] = { svb[cb][2 * w], svb[cb][2 * w + 1] };
        float gr[2]; float pbv = 0.f;
        #pragma unroll
        for (int r = 0; r < 2; ++r) {
            int rw = 2 * w + r;
            float4 a1 = *(const float4*)&s1p[rw * 4];
            float4 a2 = *(const float4*)&s2p[rw * 4];
            float s1 = a1.x + a1.y + a1.z + a1.w;
            float s2 = a2.x + a2.y + a2.z + a2.w;
            float mu = s1 * (1.f / 64.f);
            float var = s2 * (1.f / 64.f) - mu * mu;
            float rstd = rsqrtf(var + 1e-6f);
            float xh = (zar[r] - mu) * rstd;
            float g = (lnwr * xh + lnbr - (xv_rm[r] - xk_rm[r])) * lnwr;
            float sg = wsum64(g);
            float sxg = wsum64(xh * g);
            gr[r] = (64.f * g - sg - xh * sxg) * rstd * (1.f / 64.f);
            pbv += svr[r] * gr[r];
        }
        {
            ushort2 gp, sp;
            gp.x = f2bf(gr[0]); gp.y = f2bf(gr[1]);
            sp.x = f2bf(svr[0] * xk_rm[0]); sp.y = f2bf(svr[1] * xk_rm[1]);
            *(ushort2*)&gbufT[lane * 32 + 2 * w] = gp;
            *(ushort2*)&sxkT[lane * 32 + 2 * w] = sp;
            pb[w * 64 + lane] = pbv;
        }
        bsync(); // B2

        // ======== C-region ========
        bf16x8 gF = *(const bf16x8*)&gbufT[gc * 32 + 8 * q];
        if (role == 0) {
            #pragma unroll
            for (int tm = 0; tm < 4; ++tm) {
                bf16x8 ax = *(const bf16x8*)&sxkT[(16 * tm + n) * 32 + 8 * q];
                f32x4 dl = __builtin_amdgcn_mfma_f32_16x16x32_bf16(ax, gF, zero4, 0, 0, 0);
                int ko = 16 * tm + 4 * q;
                ushort4 h4 = *(ushort4*)&wt_hi[gc * 72 + ko];
                ushort4 l4 = *(ushort4*)&wt_lo[gc * 72 + ko];
                float w0 = b2f(h4.x) + b2f(l4.x) - dl[0];
                float w1 = b2f(h4.y) + b2f(l4.y) - dl[1];
                float w2 = b2f(h4.z) + b2f(l4.z) - dl[2];
                float w3 = b2f(h4.w) + b2f(l4.w) - dl[3];
                h4.x = f2bf(w0); l4.x = f2bf(w0 - b2f(h4.x));
                h4.y = f2bf(w1); l4.y = f2bf(w1 - b2f(h4.y));
                h4.z = f2bf(w2); l4.z = f2bf(w2 - b2f(h4.z));
                h4.w = f2bf(w3); l4.w = f2bf(w3 - b2f(h4.w));
                *(ushort4*)&wt_hi[gc * 72 + ko] = h4;
                *(ushort4*)&wt_lo[gc * 72 + ko] = l4;
            }
        } else {
            bf16x8 amF = *(const bf16x8*)&attb[cb][n * 32 + 8 * q];
            zb = __builtin_amdgcn_mfma_f32_16x16x32_bf16(amF, gF, zb, 0, 0, 0);
            float pz1[4], pz2[4];
            #pragma unroll
            for (int r = 0; r < 4; ++r) {
                zbar_p[r] = zb[r] + b1c;
                pz1[r] = rsum16(zbar_p[r]);
                pz2[r] = rsum16(zbar_p[r] * zbar_p[r]);
                xqc_p[r] = xqs[(4 * q + r) * 68 + gc];
            }
            if (n < 4) {
                s1z[(4 * q + n) * 4 + wz] = sel4(n, pz1[0], pz1[1], pz1[2], pz1[3]);
                s2z[(4 * q + n) * 4 + wz] = sel4(n, pz2[0], pz2[1], pz2[2], pz2[3]);
            }
        }
        {
            float sbr = 0.f, sbc = 0.f;
            #pragma unroll
            for (int i = 0; i < 8; ++i) { sbr += pb[i * 64 + lane]; sbc += pb[i * 64 + gc]; }
            b1r -= sbr; b1c -= sbc;
        }
        bsync(); // B3
    }

    // ---- epilogue: flush deferred phase D for step NMBc-1 (role1) ----
    if (role == 1) {
        int l0p = (NMBc - 1) * 16;
        #pragma unroll
        for (int r = 0; r < 4; ++r) {
            int row = 4 * q + r;
            float4 a1 = *(const float4*)&s1z[row * 4];
            float4 a2 = *(const float4*)&s2z[row * 4];
            float s1 = a1.x + a1.y + a1.z + a1.w;
            float s2 = a2.x + a2.y + a2.z + a2.w;
            float mu = s1 * (1.f / 64.f);
            float var = s2 * (1.f / 64.f) - mu * mu;
            float rstd = rsqrtf(var + 1e-6f);
            float o = lnwc * ((zbar_p[r] - mu) * rstd) + lnbc + xqc_p[r];
            Y[gbase + (size_t)(l0p + row) * Dd + gc] = o;
        }
    }
}

// ---------------- post layernorm over D + cast to bf16 ----------------
__global__ __launch_bounds__(256) void postnorm_kernel(const float* __restrict__ Y,
                                                       const float* __restrict__ pw,
                                                       const float* __restrict__ pb,
                                                       unsigned short* __restrict__ Yb) {
    int tok = blockIdx.x, t = threadIdx.x;
    const float* row = Y + (size_t)tok * Dd;
    int c0 = t * 4, c1 = 1024 + t * 4;
    float4 v0 = *(const float4*)(row + c0);
    float4 v1 = *(const float4*)(row + c1);
    float s1 = v0.x + v0.y + v0.z + v0.w + v1.x + v1.y + v1.z + v1.w;
    float s2 = v0.x * v0.x + v0.y * v0.y + v0.z * v0.z + v0.w * v0.w +
               v1.x * v1.x + v1.y * v1.y + v1.z * v1.z + v1.w * v1.w;
    s1 = wsum64(s1); s2 = wsum64(s2);
    __shared__ float r1[4], r2[4];
    if ((t & 63) == 0) { r1[t >> 6] = s1; r2[t >> 6] = s2; }
    __syncthreads();
    float S1 = r1[0] + r1[1] + r1[2] + r1[3];
    float S2 = r2[0] + r2[1] + r2[2] + r2[3];
    float mu = S1 * (1.f / 2048.f);
    float var = S2 * (1.f / 2048.f) - mu * mu;
    float rstd = rsqrtf(var + 1e-6f);
    float4 w0 = *(const float4*)(pw + c0), b0 = *(const float4*)(pb + c0);
    float4 w1 = *(const float4*)(pw + c1), b1 = *(const float4*)(pb + c1);
    ushort4 o0, o1;
    o0.x = f2bf((v0.x - mu) * rstd * w0.x + b0.x);
    o0.y = f2bf((v0.y - mu) * rstd * w0.y + b0.y);
    o0.z = f2bf((v0.z - mu) * rstd * w0.z + b0.z);
    o0.w = f2bf((v0.w - mu) * rstd * w0.w + b0.w);
    o1.x = f2bf((v1.x - mu) * rstd * w1.x + b1.x);
    o1.y = f2bf((v1.y - mu) * rstd * w1.y + b1.y);
    o1.z = f2bf((v1.z - mu) * rstd * w1.z + b1.z);
    o1.w = f2bf((v1.w - mu) * rstd * w1.w + b1.w);
    *(ushort4*)(Yb + (size_t)tok * Dd + c0) = o0;
    *(ushort4*)(Yb + (size_t)tok * Dd + c1) = o1;
}

extern "C" void kernel_launch(void* const* d_in, const int* in_sizes, int n_in,
                              void* d_out, int out_size, void* d_ws, size_t ws_size,
                              hipStream_t stream) {
    const float* hs   = (const float*)d_in[0];
    const float* wq_w = (const float*)d_in[1];
    const float* wq_b = (const float*)d_in[2];
    const float* wk_w = (const float*)d_in[3];
    const float* wk_b = (const float*)d_in[4];
    const float* wv_w = (const float*)d_in[5];
    const float* wv_b = (const float*)d_in[6];
    const float* wo_w = (const float*)d_in[7];
    const float* wo_b = (const float*)d_in[8];
    const float* lnw  = (const float*)d_in[9];
    const float* lnb  = (const float*)d_in[10];
    const float* lr_w = (const float*)d_in[11];
    const float* lr_b = (const float*)d_in[12];
    const float* W1   = (const float*)d_in[13];
    const float* b1   = (const float*)d_in[14];
    const float* pnw  = (const float*)d_in[15];
    const float* pnb  = (const float*)d_in[16];
    float* out = (float*)d_out;

    char* ws = (char*)d_ws;
    size_t off = 0;
    auto alloc = [&](size_t bytes) -> void* {
        void* p = ws + off; off += (bytes + 255) & ~(size_t)255; return p;
    };
    unsigned short* hsb = (unsigned short*)alloc((size_t)MTOK * Dd * 2);
    unsigned short* wtb = (unsigned short*)alloc((size_t)Dd * Dd * 2);
    float* XQ = (float*)alloc((size_t)MTOK * Dd * 4);
    float* XK = (float*)alloc((size_t)MTOK * Dd * 4);
    float* XV = (float*)alloc((size_t)MTOK * Dd * 4);
    float* lrbuf = (float*)alloc((size_t)Bb * Hh * Ls * 4);
    float* Y = XQ;                 // safe alias (per-chain row/col ownership; writes trail reads)
    unsigned short* Yb = hsb;      // hsb dead after QKV GEMMs

    dim3 blk(256);
    dim3 gblk(512);
    dim3 ggrid((MTOK / 256) * (Dd / 256));   // 32 x 8 = 256 workgroups (1/CU)

    cast_hs_kernel<<<dim3(MTOK * Dd / 1024), blk, 0, stream>>>(hs, hsb);

    transpose_cast_kernel<<<dim3(1024), blk, 0, stream>>>(wq_w, wtb);
    gemm256_kernel<<<ggrid, gblk, 0, stream>>>(hsb, wtb, wq_b, XQ, MTOK, Dd, Dd);
    transpose_cast_kernel<<<dim3(1024), blk, 0, stream>>>(wk_w, wtb);
    gemm256_kernel<<<ggrid, gblk, 0, stream>>>(hsb, wtb, wk_b, XK, MTOK, Dd, Dd);
    transpose_cast_kernel<<<dim3(1024), blk, 0, stream>>>(wv_w, wtb);
    gemm256_kernel<<<ggrid, gblk, 0, stream>>>(hsb, wtb, wv_b, XV, MTOK, Dd, Dd);

    lr_kernel<<<dim3(MTOK), blk, 0, stream>>>(hs, lr_w, lr_b, lrbuf);

    scan_kernel<<<dim3(Bb * Hh), dim3(512), 0, stream>>>(XQ, XK, XV, lrbuf, W1, b1, lnw, lnb, Y);

    postnorm_kernel<<<dim3(MTOK), blk, 0, stream>>>(Y, pnw, pnb, Yb);

    transpose_cast_kernel<<<dim3(1024), blk, 0, stream>>>(wo_w, wtb);
    gemm256_kernel<<<ggrid, gblk, 0, stream>>>(Yb, wtb, wo_b, out, MTOK, Dd, Dd);
}